// Round 20
// baseline (93.855 us; speedup 1.0000x reference)
//
#include <hip/hip_runtime.h>

#define NS 128
#define NRAYS 8192
#define GRID16_BYTES 16777216u   // 262144 voxels * 32 ch * 2 B
#define GRID32_BYTES 33554432u   // 262144 voxels * 32 ch * 4 B
#define WSB_BYTES 12288u

typedef unsigned short u16;
typedef unsigned int   u32;
typedef unsigned short u16x8 __attribute__((ext_vector_type(8)));
typedef __bf16 b16x8 __attribute__((ext_vector_type(8)));
typedef float f32x4 __attribute__((ext_vector_type(4)));
typedef float f32x2 __attribute__((ext_vector_type(2)));
typedef _Float16 h16x2 __attribute__((ext_vector_type(2)));
typedef unsigned int u32x4 __attribute__((ext_vector_type(4)));
typedef unsigned int u32x2 __attribute__((ext_vector_type(2)));
typedef float f32x2u __attribute__((ext_vector_type(2), aligned(4)));
typedef float f32x4u __attribute__((ext_vector_type(4), aligned(4)));

__device__ __forceinline__ float clampf(float x, float lo, float hi) {
    return fminf(fmaxf(x, lo), hi);
}

__device__ __forceinline__ u16 f2bf(float f) {
    return __builtin_bit_cast(u16, (__bf16)f);
}

__device__ __forceinline__ u32 pk2bf(float lo, float hi) {
    return (u32)f2bf(lo) | ((u32)f2bf(hi) << 16);
}

__device__ __forceinline__ u32 pkh(float a, float b) {
    h16x2 v; v[0] = (_Float16)a; v[1] = (_Float16)b;
    return __builtin_bit_cast(u32, v);
}
__device__ __forceinline__ float2 uph(u32 u) {
    h16x2 v = __builtin_bit_cast(h16x2, u);
    return make_float2((float)v[0], (float)v[1]);
}
__device__ __forceinline__ f32x2 uph2(u32 u) {
    h16x2 v = __builtin_bit_cast(h16x2, u);
    f32x2 r; r[0] = (float)v[0]; r[1] = (float)v[1];
    return r;
}
// unpack a bf16 pair word -> f32x2
__device__ __forceinline__ f32x2 up2(u32 u) {
    f32x2 r;
    r[0] = __builtin_bit_cast(float, u << 16);
    r[1] = __builtin_bit_cast(float, u & 0xffff0000u);
    return r;
}

__device__ __forceinline__ f32x4 mfma_bf16(u16x8 a, u16x8 b, f32x4 c) {
    return __builtin_amdgcn_mfma_f32_16x16x32_bf16(
        __builtin_bit_cast(b16x8, a), __builtin_bit_cast(b16x8, b), c, 0, 0, 0);
}

#define TSW(n, k) ((((n) * 64) + (k)) ^ (((n) & 7) << 3))

__device__ __forceinline__ void plane_interp(const float* __restrict__ g,
                                             float ca, float cb, float o[3]) {
    float pa = clampf((ca + 1.f) * (0.5f * 127.f), 0.f, 127.f);
    float pb = clampf((cb + 1.f) * (0.5f * 127.f), 0.f, 127.f);
    int la = (int)pa; if (la > 126) la = 126;
    int lb = (int)pb; if (lb > 126) lb = 126;
    float fa = pa - (float)la, fb = pb - (float)lb;
    const float* p = g + la * 128 + lb;
#pragma unroll
    for (int c = 0; c < 3; ++c) {
        const float* q = p + c * 16384;
        f32x2u q0 = *(const f32x2u*)q;
        f32x2u q1 = *(const f32x2u*)(q + 128);
        float top = fmaf(q0[1] - q0[0], fb, q0[0]);
        float bot = fmaf(q1[1] - q1[0], fb, q1[0]);
        o[c] = fmaf(bot - top, fa, top);
    }
}

__device__ __forceinline__ void weight_pack_item(
    int idx, const float* __restrict__ w1, const float* __restrict__ wc1,
    const float* __restrict__ w2, const float* __restrict__ wc2,
    const float* __restrict__ bc1, u16* __restrict__ wsb)
{
    int lane = (idx >> 3) & 63;
    int j = idx & 7;
    int c16 = lane & 15, kg = lane >> 4;
    float v;
    if (idx < 2048) {
        int nb = idx >> 9;
        int k = kg * 8 + j;
        v = w1[k * 64 + nb * 16 + c16];
    } else if (idx < 4096) {
        int nb = (idx - 2048) >> 9;
        int k = kg * 8 + j;
        if (k == 0)       v = 0.f;
        else if (k < 16)  v = wc1[(k + 2) * 64 + nb * 16 + c16];
        else if (k < 19)  v = wc1[(k - 16) * 64 + nb * 16 + c16];
        else if (k == 19) v = bc1[nb * 16 + c16];
        else              v = 0.f;
    } else if (idx < 5120) {
        int ks = (idx - 4096) >> 9;
        int k = ks * 32 + kg * 8 + j;
        v = w2[k * 16 + c16];
    } else {
        int ks = (idx - 5120) >> 9;
        int k = ks * 32 + kg * 8 + j;
        v = (c16 < 3) ? wc2[k * 3 + c16] : 0.f;
    }
    wsb[idx] = f2bf(v);
}

// ---- merged prep: blocks 0..1023 repack grid (mode 2 = f32, 1 = bf16);
//      blocks 1024..1047 pack weight A-fragments ----
__global__ __launch_bounds__(256)
void prep_all(const float* __restrict__ f, u16* __restrict__ g16,
              float* __restrict__ g32, int mode,
              const float* __restrict__ w1, const float* __restrict__ wc1,
              const float* __restrict__ w2, const float* __restrict__ wc2,
              const float* __restrict__ bc1, u16* __restrict__ wsb)
{
    int bid = blockIdx.x;
    if (bid < 1024) {
        int vox = bid * 256 + threadIdx.x;
        if (mode == 2) {
            float vals[32];
#pragma unroll
            for (int c = 0; c < 32; ++c)
                vals[c] = f[(size_t)c * 262144 + vox];
            f32x4* o = (f32x4*)(g32 + (size_t)vox * 32);
#pragma unroll
            for (int k = 0; k < 8; ++k) {
                f32x4 w;
                w[0] = vals[k * 4]; w[1] = vals[k * 4 + 1];
                w[2] = vals[k * 4 + 2]; w[3] = vals[k * 4 + 3];
                o[k] = w;
            }
        } else {
            u32 acc[16];
#pragma unroll
            for (int c = 0; c < 32; c += 2) {
                float a = f[(size_t)c * 262144 + vox];
                float b = f[(size_t)(c + 1) * 262144 + vox];
                acc[c >> 1] = pk2bf(a, b);
            }
            u32x4* o = (u32x4*)(g16 + (size_t)vox * 32);
#pragma unroll
            for (int k = 0; k < 4; ++k) {
                u32x4 w; w[0] = acc[k * 4]; w[1] = acc[k * 4 + 1];
                w[2] = acc[k * 4 + 2]; w[3] = acc[k * 4 + 3];
                o[k] = w;
            }
        }
    } else {
        int idx = (bid - 1024) * 256 + threadIdx.x;
        if (idx < 6144) weight_pack_item(idx, w1, wc1, w2, wc2, bc1, wsb);
    }
}

// ---- standalone weight prep (tiny-ws fallback path) ----
__global__ __launch_bounds__(256)
void prep_weights(const float* __restrict__ w1, const float* __restrict__ wc1,
                  const float* __restrict__ w2, const float* __restrict__ wc2,
                  const float* __restrict__ bc1, u16* __restrict__ wsb)
{
    int idx = blockIdx.x * 256 + threadIdx.x;
    if (idx < 6144) weight_pack_item(idx, w1, wc1, w2, wc2, bc1, wsb);
}

#define RELUSTORE(ACC, NB) {                                           \
        f32x2 lo_; lo_[0] = (ACC)[0]; lo_[1] = (ACC)[1];               \
        f32x2 hi_; hi_[0] = (ACC)[2]; hi_[1] = (ACC)[3];               \
        f32x2 z2_; z2_[0] = 0.f; z2_[1] = 0.f;                         \
        lo_ = __builtin_elementwise_max(lo_, z2_);                     \
        hi_ = __builtin_elementwise_max(hi_, z2_);                     \
        u32x2 wr_;                                                     \
        wr_[0] = pk2bf(lo_[0], lo_[1]);                                \
        wr_[1] = pk2bf(hi_[0], hi_[1]);                                \
        *(u32x2*)&s_tile[wv][TSW(c16, (NB) * 16 + kg * 4)] = wr_; }

// bf16-grid corner combine
#define CORNER(Q, W) {                                                 \
        f32x2 ws_; ws_[0] = (W); ws_[1] = (W);                         \
        p0 = __builtin_elementwise_fma(up2((Q)[0]), ws_, p0);          \
        p1 = __builtin_elementwise_fma(up2((Q)[1]), ws_, p1);          \
        p2 = __builtin_elementwise_fma(up2((Q)[2]), ws_, p2);          \
        p3 = __builtin_elementwise_fma(up2((Q)[3]), ws_, p3); }

// f32-grid corner combine: QA = ch0-3, QB = ch4-7 (no unpack needed)
#define CORNER32(QA, QB, W) {                                          \
        f32x2 ws_; ws_[0] = (W); ws_[1] = (W);                         \
        f32x2 a0_; a0_[0] = (QA)[0]; a0_[1] = (QA)[1];                 \
        f32x2 a1_; a1_[0] = (QA)[2]; a1_[1] = (QA)[3];                 \
        f32x2 b0_; b0_[0] = (QB)[0]; b0_[1] = (QB)[1];                 \
        f32x2 b1_; b1_[0] = (QB)[2]; b1_[1] = (QB)[3];                 \
        p0 = __builtin_elementwise_fma(a0_, ws_, p0);                  \
        p1 = __builtin_elementwise_fma(a1_, ws_, p1);                  \
        p2 = __builtin_elementwise_fma(b0_, ws_, p2);                  \
        p3 = __builtin_elementwise_fma(b1_, ws_, p3); }

// shared prologue/epilogue; VARIADIC so commas inside the gather block are safe
#define KERNEL_BODY(...)                                               \
    __shared__ __align__(16) u16x8 s_wfrag[512];                       \
    __shared__ __align__(16) float s_bias[96];                         \
    __shared__ __align__(16) u32x4 s_cw[4][128];                       \
    __shared__ u32   s_fb[4][128];                                     \
    __shared__ __align__(16) u16  s_tile[4][16 * 64];                  \
    __shared__ float s_tau[4][128];                                    \
    __shared__ u32   s_rgbrg[4][128];                                  \
    __shared__ u16   s_rgbb[4][128];                                   \
    const int tid  = threadIdx.x;                                      \
    const int wv   = tid >> 6;                                         \
    const int lane = tid & 63;                                         \
    const int c16  = lane & 15;                                        \
    const int kg   = lane >> 4;                                        \
    const int ray  = blockIdx.x * 4 + wv;                              \
    const int sA   = c16 + 16 * ((2 * kg) & 3);                        \
    const int sB   = c16 + 16 * ((2 * kg + 1) & 3);                    \
    u16x8 AW2[2], AWc2[2];                                             \
    {                                                                  \
        const u16x8* wf = (const u16x8*)wsb;                           \
        _Pragma("unroll")                                              \
        for (int i = 0; i < 2; ++i)                                    \
            s_wfrag[tid + 256 * i] = wf[tid + 256 * i];                \
        _Pragma("unroll")                                              \
        for (int ks = 0; ks < 2; ++ks) {                               \
            AW2[ks]  = wf[512 + ks * 64 + lane];                       \
            AWc2[ks] = wf[640 + ks * 64 + lane];                       \
        }                                                              \
    }                                                                  \
    if (tid < 96) {                                                    \
        float v;                                                       \
        if (tid < 64)      v = b1[tid];                                \
        else if (tid < 80) v = b2[tid - 64];                           \
        else               v = (tid - 80 < 3) ? bc2[tid - 80] : 0.f;   \
        s_bias[tid] = v;                                               \
    }                                                                  \
    float ox = rays_o[ray * 3 + 0], oy = rays_o[ray * 3 + 1], oz = rays_o[ray * 3 + 2]; \
    float dx = rays_d[ray * 3 + 0], dy = rays_d[ray * 3 + 1], dz = rays_d[ray * 3 + 2]; \
    float rn = rsqrtf(dx * dx + dy * dy + dz * dz);                    \
    dx *= rn; dy *= rn; dz *= rn;                                      \
    float lo0 = aabb[0], lo1 = aabb[1], lo2 = aabb[2];                 \
    float hi0 = aabb[3], hi1 = aabb[4], hi2 = aabb[5];                 \
    float invx = 1.f / dx, invy = 1.f / dy, invz = 1.f / dz;           \
    float tx0 = (lo0 - ox) * invx, tx1 = (hi0 - ox) * invx;            \
    float ty0 = (lo1 - oy) * invy, ty1 = (hi1 - oy) * invy;            \
    float tz0 = (lo2 - oz) * invz, tz1 = (hi2 - oz) * invz;            \
    float tnear = fmaxf(fmaxf(fminf(tx0, tx1), fminf(ty0, ty1)), fminf(tz0, tz1)); \
    tnear = fmaxf(tnear, 0.f);                                         \
    float tfar = fminf(fminf(fmaxf(tx0, tx1), fmaxf(ty0, ty1)), fmaxf(tz0, tz1)); \
    tfar = fmaxf(tfar, tnear);                                         \
    float delta = (tfar - tnear) * (1.f / (float)NS);                  \
    const u32 dir01 = pk2bf(dx, dy);                                   \
    const u32 dir2b = pk2bf(dz, 1.0f);                                 \
    _Pragma("unroll")                                                  \
    for (int i = 0; i < 2; ++i) {                                      \
        int s = i * 64 + lane;                                         \
        float t = tnear + delta * ((float)s + 0.5f);                   \
        float px = ox + dx * t, py = oy + dy * t, pz = oz + dz * t;    \
        px = (px - lo0) * (2.f / (hi0 - lo0)) - 1.f;                   \
        py = (py - lo1) * (2.f / (hi1 - lo1)) - 1.f;                   \
        pz = (pz - lo2) * (2.f / (hi2 - lo2)) - 1.f;                   \
        float p01[3], p02[3], p12[3];                                  \
        plane_interp(plane01, px, py, p01);                            \
        plane_interp(plane02, px, pz, p02);                            \
        plane_interp(plane12, py, pz, p12);                            \
        float gx = p01[0] * p02[0] * p12[0];                           \
        float gy = p01[1] * p02[1] * p12[1];                           \
        float gz = p01[2] * p02[2] * p12[2];                           \
        float qx = clampf((gx + 1.f) * (0.5f * 63.f), 0.f, 63.f);      \
        float qy = clampf((gy + 1.f) * (0.5f * 63.f), 0.f, 63.f);      \
        float qz = clampf((gz + 1.f) * (0.5f * 63.f), 0.f, 63.f);      \
        int ixg = (int)qx; if (ixg > 62) ixg = 62;                     \
        int iyg = (int)qy; if (iyg > 62) iyg = 62;                     \
        int izg = (int)qz; if (izg > 62) izg = 62;                     \
        float fx = qx - (float)ixg, fy = qy - (float)iyg, fz = qz - (float)izg; \
        float wx0 = 1.f - fx, wy0 = 1.f - fy, wz0 = 1.f - fz;          \
        u32x4 cw;                                                      \
        cw[0] = pkh(wx0 * wy0 * wz0, wx0 * wy0 * fz);                  \
        cw[1] = pkh(wx0 * fy  * wz0, wx0 * fy  * fz);                  \
        cw[2] = pkh(fx  * wy0 * wz0, fx  * wy0 * fz);                  \
        cw[3] = pkh(fx  * fy  * wz0, fx  * fy  * fz);                  \
        s_cw[wv][s] = cw;                                              \
        s_fb[wv][s] = (u32)(ixg * 4096 + iyg * 64 + izg);              \
    }                                                                  \
    __syncthreads();                                                   \
    _Pragma("unroll 1")                                                \
    for (int c = 0; c < 8; ++c) {                                      \
        u32x4 cwp = s_cw[wv][c * 16 + c16];                            \
        u32 vidx = s_fb[wv][c * 16 + c16];                             \
        f32x2 w0v = uph2(cwp[0]);                                      \
        f32x2 w1v = uph2(cwp[1]);                                      \
        f32x2 w2v = uph2(cwp[2]);                                      \
        f32x2 w3v = uph2(cwp[3]);                                      \
        u32x4 a1v;                                                     \
        { __VA_ARGS__ }                                                \
        u16x8 a1 = __builtin_bit_cast(u16x8, a1v);                     \
        f32x4 g0 = mfma_bf16(s_wfrag[0 * 64 + lane], a1, *(const f32x4*)&s_bias[0 * 16 + kg * 4]); \
        f32x4 g1 = mfma_bf16(s_wfrag[1 * 64 + lane], a1, *(const f32x4*)&s_bias[1 * 16 + kg * 4]); \
        f32x4 g2 = mfma_bf16(s_wfrag[2 * 64 + lane], a1, *(const f32x4*)&s_bias[2 * 16 + kg * 4]); \
        f32x4 g3 = mfma_bf16(s_wfrag[3 * 64 + lane], a1, *(const f32x4*)&s_bias[3 * 16 + kg * 4]); \
        RELUSTORE(g0, 0); RELUSTORE(g1, 1); RELUSTORE(g2, 2); RELUSTORE(g3, 3); \
        u16x8 B2_0 = *(const u16x8*)&s_tile[wv][TSW(c16, kg * 8)];     \
        u16x8 B2_1 = *(const u16x8*)&s_tile[wv][TSW(c16, 32 + kg * 8)];\
        f32x4 so = mfma_bf16(AW2[0], B2_0, *(const f32x4*)&s_bias[64 + kg * 4]); \
        so = mfma_bf16(AW2[1], B2_1, so);                              \
        if (kg == 0) {                                                 \
            float dens = __expf(clampf(so[0], -15.f, 15.f));           \
            s_tau[wv][c * 16 + c16] = dens * delta;                    \
        }                                                              \
        u32 Q0 = pk2bf(so[0], so[1]);                                  \
        u32 Q1 = pk2bf(so[2], so[3]);                                  \
        u32x4 ct;                                                      \
        ct[0] = (u32)__shfl((int)Q0, sA);                              \
        ct[1] = (u32)__shfl((int)Q1, sA);                              \
        ct[2] = (u32)__shfl((int)Q0, sB);                              \
        ct[3] = (u32)__shfl((int)Q1, sB);                              \
        if (kg == 2) { ct[0] = dir01; ct[1] = dir2b; ct[2] = 0u; ct[3] = 0u; } \
        if (kg == 3) { ct[0] = 0u; ct[1] = 0u; ct[2] = 0u; ct[3] = 0u; } \
        u16x8 bcin = __builtin_bit_cast(u16x8, ct);                    \
        f32x4 zz; zz[0] = zz[1] = zz[2] = zz[3] = 0.f;                 \
        f32x4 h0 = mfma_bf16(s_wfrag[256 + 0 * 64 + lane], bcin, zz);  \
        f32x4 h1 = mfma_bf16(s_wfrag[256 + 1 * 64 + lane], bcin, zz);  \
        f32x4 h2 = mfma_bf16(s_wfrag[256 + 2 * 64 + lane], bcin, zz);  \
        f32x4 h3 = mfma_bf16(s_wfrag[256 + 3 * 64 + lane], bcin, zz);  \
        RELUSTORE(h0, 0); RELUSTORE(h1, 1); RELUSTORE(h2, 2); RELUSTORE(h3, 3); \
        u16x8 B4_0 = *(const u16x8*)&s_tile[wv][TSW(c16, kg * 8)];     \
        u16x8 B4_1 = *(const u16x8*)&s_tile[wv][TSW(c16, 32 + kg * 8)];\
        f32x4 cacc = mfma_bf16(AWc2[0], B4_0, *(const f32x4*)&s_bias[80 + kg * 4]); \
        cacc = mfma_bf16(AWc2[1], B4_1, cacc);                         \
        if (kg == 0) {                                                 \
            int si = c * 16 + c16;                                     \
            float r = 1.f / (1.f + __expf(-cacc[0]));                  \
            float g = 1.f / (1.f + __expf(-cacc[1]));                  \
            float b = 1.f / (1.f + __expf(-cacc[2]));                  \
            s_rgbrg[wv][si] = pkh(r, g);                               \
            s_rgbb[wv][si] = (u16)(pkh(b, 0.f) & 0xffffu);             \
        }                                                              \
    }                                                                  \
    float t0 = s_tau[wv][lane];                                        \
    float t1 = s_tau[wv][64 + lane];                                   \
    float x0 = t0, x1 = t1;                                            \
    _Pragma("unroll")                                                  \
    for (int off = 1; off < 64; off <<= 1) {                           \
        float y = __shfl_up(x0, off);                                  \
        if (lane >= off) x0 += y;                                      \
    }                                                                  \
    float tot0 = __shfl(x0, 63);                                       \
    _Pragma("unroll")                                                  \
    for (int off = 1; off < 64; off <<= 1) {                           \
        float y = __shfl_up(x1, off);                                  \
        if (lane >= off) x1 += y;                                      \
    }                                                                  \
    x1 += tot0;                                                        \
    float w0 = __expf(t0 - x0) * (1.f - __expf(-t0));                  \
    float w1s = __expf(t1 - x1) * (1.f - __expf(-t1));                 \
    float2 rg0 = uph(s_rgbrg[wv][lane]);                               \
    float2 rg1 = uph(s_rgbrg[wv][64 + lane]);                          \
    float bb0 = uph((u32)s_rgbb[wv][lane]).x;                          \
    float bb1 = uph((u32)s_rgbb[wv][64 + lane]).x;                     \
    float v0 = w0 * rg0.x + w1s * rg1.x;                               \
    float v1 = w0 * rg0.y + w1s * rg1.y;                               \
    float v2 = w0 * bb0 + w1s * bb1;                                   \
    float v3 = w0 + w1s;                                               \
    _Pragma("unroll")                                                  \
    for (int off = 32; off; off >>= 1) {                               \
        v0 += __shfl_xor(v0, off);                                     \
        v1 += __shfl_xor(v1, off);                                     \
        v2 += __shfl_xor(v2, off);                                     \
        v3 += __shfl_xor(v3, off);                                     \
    }                                                                  \
    if (lane == 0) {                                                   \
        float bg = bg_color[0];                                        \
        out[ray * 3 + 0] = v0 + (1.f - v3) * bg;                       \
        out[ray * 3 + 1] = v1 + (1.f - v3) * bg;                       \
        out[ray * 3 + 2] = v2 + (1.f - v3) * bg;                       \
    }

// ---- HOT kernel A: f32 channel-last grid (no unpack in combine) ----
__global__ __launch_bounds__(256)
void nerf_mfma_grid32(const float* __restrict__ rays_o,
                      const float* __restrict__ rays_d,
                      const float* __restrict__ bg_color,
                      const float* __restrict__ plane01,
                      const float* __restrict__ plane02,
                      const float* __restrict__ plane12,
                      const float* __restrict__ b1, const float* __restrict__ b2,
                      const float* __restrict__ bc2,
                      const float* __restrict__ aabb,
                      float* __restrict__ out,
                      const u16* __restrict__ wsb,
                      const float* __restrict__ wsg)
{
    const char* gby = (const char*)wsg;
    KERNEL_BODY(
        u32 o0  = vidx * 128u + (u32)(kg * 32);
        u32 oy  = o0 + 8192u;      // iy+1
        u32 ox  = o0 + 524288u;    // ix+1
        u32 oxy = o0 + 532480u;    // ix+1, iy+1
        f32x4u q00a = *(const f32x4u*)(gby + o0);
        f32x4u q00b = *(const f32x4u*)(gby + o0 + 16);
        f32x4u q01a = *(const f32x4u*)(gby + o0 + 128);
        f32x4u q01b = *(const f32x4u*)(gby + o0 + 144);
        f32x4u q10a = *(const f32x4u*)(gby + oy);
        f32x4u q10b = *(const f32x4u*)(gby + oy + 16);
        f32x4u q11a = *(const f32x4u*)(gby + oy + 128);
        f32x4u q11b = *(const f32x4u*)(gby + oy + 144);
        f32x4u q20a = *(const f32x4u*)(gby + ox);
        f32x4u q20b = *(const f32x4u*)(gby + ox + 16);
        f32x4u q21a = *(const f32x4u*)(gby + ox + 128);
        f32x4u q21b = *(const f32x4u*)(gby + ox + 144);
        f32x4u q30a = *(const f32x4u*)(gby + oxy);
        f32x4u q30b = *(const f32x4u*)(gby + oxy + 16);
        f32x4u q31a = *(const f32x4u*)(gby + oxy + 128);
        f32x4u q31b = *(const f32x4u*)(gby + oxy + 144);
        f32x2 p0, p1, p2, p3;
        p0[0] = p0[1] = 0.f; p1 = p0; p2 = p0; p3 = p0;
        CORNER32(q00a, q00b, w0v[0]); CORNER32(q01a, q01b, w0v[1]);
        CORNER32(q10a, q10b, w1v[0]); CORNER32(q11a, q11b, w1v[1]);
        CORNER32(q20a, q20b, w2v[0]); CORNER32(q21a, q21b, w2v[1]);
        CORNER32(q30a, q30b, w3v[0]); CORNER32(q31a, q31b, w3v[1]);
        a1v[0] = pk2bf(p0[0], p0[1]);
        a1v[1] = pk2bf(p1[0], p1[1]);
        a1v[2] = pk2bf(p2[0], p2[1]);
        a1v[3] = pk2bf(p3[0], p3[1]);
    )
}

// ---- HOT kernel B: bf16 channel-last grid ----
__global__ __launch_bounds__(256)
void nerf_mfma_grid(const float* __restrict__ rays_o,
                    const float* __restrict__ rays_d,
                    const float* __restrict__ bg_color,
                    const float* __restrict__ plane01,
                    const float* __restrict__ plane02,
                    const float* __restrict__ plane12,
                    const float* __restrict__ b1, const float* __restrict__ b2,
                    const float* __restrict__ bc2,
                    const float* __restrict__ aabb,
                    float* __restrict__ out,
                    const u16* __restrict__ wsb,
                    const u16* __restrict__ wsg)
{
    const char* gby = (const char*)wsg;
    KERNEL_BODY(
        u32 o0  = vidx * 64u + (u32)(kg * 16);
        u32 oy  = o0 + 4096u;
        u32 ox  = o0 + 262144u;
        u32 oxy = o0 + 266240u;
        u32x4 q00 = *(const u32x4*)(gby + o0);
        u32x4 q01 = *(const u32x4*)(gby + o0 + 64);
        u32x4 q10 = *(const u32x4*)(gby + oy);
        u32x4 q11 = *(const u32x4*)(gby + oy + 64);
        u32x4 q20 = *(const u32x4*)(gby + ox);
        u32x4 q21 = *(const u32x4*)(gby + ox + 64);
        u32x4 q30 = *(const u32x4*)(gby + oxy);
        u32x4 q31 = *(const u32x4*)(gby + oxy + 64);
        f32x2 p0, p1, p2, p3;
        p0[0] = p0[1] = 0.f; p1 = p0; p2 = p0; p3 = p0;
        CORNER(q00, w0v[0]); CORNER(q01, w0v[1]);
        CORNER(q10, w1v[0]); CORNER(q11, w1v[1]);
        CORNER(q20, w2v[0]); CORNER(q21, w2v[1]);
        CORNER(q30, w3v[0]); CORNER(q31, w3v[1]);
        a1v[0] = pk2bf(p0[0], p0[1]);
        a1v[1] = pk2bf(p1[0], p1[1]);
        a1v[2] = pk2bf(p2[0], p2[1]);
        a1v[3] = pk2bf(p3[0], p3[1]);
    )
}

// ---- fallback kernel: planar f32 gather ----
__global__ __launch_bounds__(256)
void nerf_mfma_planar(const float* __restrict__ rays_o,
                      const float* __restrict__ rays_d,
                      const float* __restrict__ bg_color,
                      const float* __restrict__ plane01,
                      const float* __restrict__ plane02,
                      const float* __restrict__ plane12,
                      const float* __restrict__ b1, const float* __restrict__ b2,
                      const float* __restrict__ bc2,
                      const float* __restrict__ aabb,
                      float* __restrict__ out,
                      const u16* __restrict__ wsb,
                      const float* __restrict__ features)
{
    const char* fby  = (const char*)features;
    const char* fby2 = fby + 16384;
    KERNEL_BODY(
        u32 chb = vidx * 4u + (u32)(kg * 8) * 1048576u;
        _Pragma("unroll")
        for (int jj = 0; jj < 4; ++jj) {
            float vv[2];
            _Pragma("unroll")
            for (int h = 0; h < 2; ++h) {
                u32 off = chb + (u32)(jj * 2 + h) * 1048576u;
                f32x2 q0 = *(const f32x2u*)(fby + off);
                f32x2 q1 = *(const f32x2u*)(fby + off + 256);
                f32x2 q2 = *(const f32x2u*)(fby2 + off);
                f32x2 q3 = *(const f32x2u*)(fby2 + off + 256);
                f32x2 acc = q0 * w0v;
                acc = __builtin_elementwise_fma(q1, w1v, acc);
                acc = __builtin_elementwise_fma(q2, w2v, acc);
                acc = __builtin_elementwise_fma(q3, w3v, acc);
                vv[h] = acc[0] + acc[1];
            }
            a1v[jj] = pk2bf(vv[0], vv[1]);
        }
    )
}

extern "C" void kernel_launch(void* const* d_in, const int* in_sizes, int n_in,
                              void* d_out, int out_size, void* d_ws, size_t ws_size,
                              hipStream_t stream) {
    const float* rays_o  = (const float*)d_in[0];
    const float* rays_d  = (const float*)d_in[1];
    const float* bg      = (const float*)d_in[2];
    const float* p01     = (const float*)d_in[3];
    const float* p02     = (const float*)d_in[4];
    const float* p12     = (const float*)d_in[5];
    const float* feats   = (const float*)d_in[6];
    const float* w1      = (const float*)d_in[7];
    const float* b1      = (const float*)d_in[8];
    const float* w2      = (const float*)d_in[9];
    const float* b2      = (const float*)d_in[10];
    const float* wc1     = (const float*)d_in[11];
    const float* bc1     = (const float*)d_in[12];
    const float* wc2     = (const float*)d_in[13];
    const float* bc2     = (const float*)d_in[14];
    const float* aabb    = (const float*)d_in[15];
    float* out = (float*)d_out;

    int mode;
    if (ws_size >= (size_t)GRID32_BYTES + WSB_BYTES)      mode = 2;
    else if (ws_size >= (size_t)GRID16_BYTES + WSB_BYTES) mode = 1;
    else                                                  mode = 0;

    if (mode == 2) {
        float* wsg32 = (float*)d_ws;
        u16* wsb = (u16*)((char*)d_ws + GRID32_BYTES);
        prep_all<<<1048, 256, 0, stream>>>(feats, nullptr, wsg32, 2,
                                           w1, wc1, w2, wc2, bc1, wsb);
        nerf_mfma_grid32<<<NRAYS / 4, 256, 0, stream>>>(
            rays_o, rays_d, bg, p01, p02, p12, b1, b2, bc2, aabb, out, wsb, wsg32);
    } else if (mode == 1) {
        u16* wsg16 = (u16*)d_ws;
        u16* wsb = (u16*)((char*)d_ws + GRID16_BYTES);
        prep_all<<<1048, 256, 0, stream>>>(feats, wsg16, nullptr, 1,
                                           w1, wc1, w2, wc2, bc1, wsb);
        nerf_mfma_grid<<<NRAYS / 4, 256, 0, stream>>>(
            rays_o, rays_d, bg, p01, p02, p12, b1, b2, bc2, aabb, out, wsb, wsg16);
    } else {
        u16* wsb = (u16*)d_ws;
        prep_weights<<<24, 256, 0, stream>>>(w1, wc1, w2, wc2, bc1, wsb);
        nerf_mfma_planar<<<NRAYS / 4, 256, 0, stream>>>(
            rays_o, rays_d, bg, p01, p02, p12, b1, b2, bc2, aabb, out, wsb, feats);
    }
}

// Round 21
// 76.682 us; speedup vs baseline: 1.2240x; 1.2240x over previous
//
#include <hip/hip_runtime.h>

#define NS 128
#define NRAYS 8192
#define GRID16_BYTES 16777216u   // 262144 voxels * 32 ch * 2 B
#define WSB_BYTES 12288u

typedef unsigned short u16;
typedef unsigned int   u32;
typedef unsigned short u16x8 __attribute__((ext_vector_type(8)));
typedef __bf16 b16x8 __attribute__((ext_vector_type(8)));
typedef float f32x4 __attribute__((ext_vector_type(4)));
typedef float f32x2 __attribute__((ext_vector_type(2)));
typedef _Float16 h16x2 __attribute__((ext_vector_type(2)));
typedef unsigned int u32x4 __attribute__((ext_vector_type(4)));
typedef unsigned int u32x2 __attribute__((ext_vector_type(2)));
typedef float f32x2u __attribute__((ext_vector_type(2), aligned(4)));

__device__ __forceinline__ float clampf(float x, float lo, float hi) {
    return fminf(fmaxf(x, lo), hi);
}

__device__ __forceinline__ u16 f2bf(float f) {
    return __builtin_bit_cast(u16, (__bf16)f);
}

__device__ __forceinline__ u32 pk2bf(float lo, float hi) {
    return (u32)f2bf(lo) | ((u32)f2bf(hi) << 16);
}

__device__ __forceinline__ u32 pkh(float a, float b) {
    h16x2 v; v[0] = (_Float16)a; v[1] = (_Float16)b;
    return __builtin_bit_cast(u32, v);
}
__device__ __forceinline__ float2 uph(u32 u) {
    h16x2 v = __builtin_bit_cast(h16x2, u);
    return make_float2((float)v[0], (float)v[1]);
}
__device__ __forceinline__ f32x2 uph2(u32 u) {
    h16x2 v = __builtin_bit_cast(h16x2, u);
    f32x2 r; r[0] = (float)v[0]; r[1] = (float)v[1];
    return r;
}
// unpack a bf16 pair word -> f32x2
__device__ __forceinline__ f32x2 up2(u32 u) {
    f32x2 r;
    r[0] = __builtin_bit_cast(float, u << 16);
    r[1] = __builtin_bit_cast(float, u & 0xffff0000u);
    return r;
}

__device__ __forceinline__ f32x4 mfma_bf16(u16x8 a, u16x8 b, f32x4 c) {
    return __builtin_amdgcn_mfma_f32_16x16x32_bf16(
        __builtin_bit_cast(b16x8, a), __builtin_bit_cast(b16x8, b), c, 0, 0, 0);
}

#define TSW(n, k) ((((n) * 64) + (k)) ^ (((n) & 7) << 3))

__device__ __forceinline__ void plane_interp(const float* __restrict__ g,
                                             float ca, float cb, float o[3]) {
    float pa = clampf((ca + 1.f) * (0.5f * 127.f), 0.f, 127.f);
    float pb = clampf((cb + 1.f) * (0.5f * 127.f), 0.f, 127.f);
    int la = (int)pa; if (la > 126) la = 126;
    int lb = (int)pb; if (lb > 126) lb = 126;
    float fa = pa - (float)la, fb = pb - (float)lb;
    const float* p = g + la * 128 + lb;
#pragma unroll
    for (int c = 0; c < 3; ++c) {
        const float* q = p + c * 16384;
        f32x2u q0 = *(const f32x2u*)q;
        f32x2u q1 = *(const f32x2u*)(q + 128);
        float top = fmaf(q0[1] - q0[0], fb, q0[0]);
        float bot = fmaf(q1[1] - q1[0], fb, q1[0]);
        o[c] = fmaf(bot - top, fa, top);
    }
}

__device__ __forceinline__ void weight_pack_item(
    int idx, const float* __restrict__ w1, const float* __restrict__ wc1,
    const float* __restrict__ w2, const float* __restrict__ wc2,
    const float* __restrict__ bc1, u16* __restrict__ wsb)
{
    int lane = (idx >> 3) & 63;
    int j = idx & 7;
    int c16 = lane & 15, kg = lane >> 4;
    float v;
    if (idx < 2048) {
        int nb = idx >> 9;
        int k = kg * 8 + j;
        v = w1[k * 64 + nb * 16 + c16];
    } else if (idx < 4096) {
        int nb = (idx - 2048) >> 9;
        int k = kg * 8 + j;
        if (k == 0)       v = 0.f;
        else if (k < 16)  v = wc1[(k + 2) * 64 + nb * 16 + c16];
        else if (k < 19)  v = wc1[(k - 16) * 64 + nb * 16 + c16];
        else if (k == 19) v = bc1[nb * 16 + c16];
        else              v = 0.f;
    } else if (idx < 5120) {
        int ks = (idx - 4096) >> 9;
        int k = ks * 32 + kg * 8 + j;
        v = w2[k * 16 + c16];
    } else {
        int ks = (idx - 5120) >> 9;
        int k = ks * 32 + kg * 8 + j;
        v = (c16 < 3) ? wc2[k * 3 + c16] : 0.f;
    }
    wsb[idx] = f2bf(v);
}

// ---- merged prep: blocks 0..1023 repack grid to bf16 channel-last;
//      blocks 1024..1047 pack weight A-fragments ----
__global__ __launch_bounds__(256)
void prep_all(const float* __restrict__ f, u16* __restrict__ g16,
              const float* __restrict__ w1, const float* __restrict__ wc1,
              const float* __restrict__ w2, const float* __restrict__ wc2,
              const float* __restrict__ bc1, u16* __restrict__ wsb)
{
    int bid = blockIdx.x;
    if (bid < 1024) {
        int vox = bid * 256 + threadIdx.x;
        u32 acc[16];
#pragma unroll
        for (int c = 0; c < 32; c += 2) {
            float a = f[(size_t)c * 262144 + vox];
            float b = f[(size_t)(c + 1) * 262144 + vox];
            acc[c >> 1] = pk2bf(a, b);
        }
        u32x4* o = (u32x4*)(g16 + (size_t)vox * 32);
#pragma unroll
        for (int k = 0; k < 4; ++k) {
            u32x4 w; w[0] = acc[k * 4]; w[1] = acc[k * 4 + 1];
            w[2] = acc[k * 4 + 2]; w[3] = acc[k * 4 + 3];
            o[k] = w;
        }
    } else {
        int idx = (bid - 1024) * 256 + threadIdx.x;
        if (idx < 6144) weight_pack_item(idx, w1, wc1, w2, wc2, bc1, wsb);
    }
}

// ---- standalone weight prep (tiny-ws fallback) ----
__global__ __launch_bounds__(256)
void prep_weights(const float* __restrict__ w1, const float* __restrict__ wc1,
                  const float* __restrict__ w2, const float* __restrict__ wc2,
                  const float* __restrict__ bc1, u16* __restrict__ wsb)
{
    int idx = blockIdx.x * 256 + threadIdx.x;
    if (idx < 6144) weight_pack_item(idx, w1, wc1, w2, wc2, bc1, wsb);
}

#define RELUSTORE(ACC, NB) {                                           \
        f32x2 lo_; lo_[0] = (ACC)[0]; lo_[1] = (ACC)[1];               \
        f32x2 hi_; hi_[0] = (ACC)[2]; hi_[1] = (ACC)[3];               \
        f32x2 z2_; z2_[0] = 0.f; z2_[1] = 0.f;                         \
        lo_ = __builtin_elementwise_max(lo_, z2_);                     \
        hi_ = __builtin_elementwise_max(hi_, z2_);                     \
        u32x2 wr_;                                                     \
        wr_[0] = pk2bf(lo_[0], lo_[1]);                                \
        wr_[1] = pk2bf(hi_[0], hi_[1]);                                \
        *(u32x2*)&s_tile[wv][TSW(c16, (NB) * 16 + kg * 4)] = wr_; }

// bf16-grid corner combine
#define CORNER(Q, W) {                                                 \
        f32x2 ws_; ws_[0] = (W); ws_[1] = (W);                         \
        p0 = __builtin_elementwise_fma(up2((Q)[0]), ws_, p0);          \
        p1 = __builtin_elementwise_fma(up2((Q)[1]), ws_, p1);          \
        p2 = __builtin_elementwise_fma(up2((Q)[2]), ws_, p2);          \
        p3 = __builtin_elementwise_fma(up2((Q)[3]), ws_, p3); }

// shared prologue/epilogue; VARIADIC so commas inside the gather block are safe.
// GEMM1/GEMM3 computed in TWO HALVES (retire nb 0-1 to LDS before nb 2-3) to
// halve peak accumulator registers (unified VGPR+AGPR footprint -> occupancy).
#define KERNEL_BODY(...)                                               \
    __shared__ __align__(16) u16x8 s_wfrag[512];                       \
    __shared__ __align__(16) float s_bias[96];                         \
    __shared__ __align__(16) u32x4 s_cw[4][128];                       \
    __shared__ u32   s_fb[4][128];                                     \
    __shared__ __align__(16) u16  s_tile[4][16 * 64];                  \
    __shared__ float s_tau[4][128];                                    \
    __shared__ u32   s_rgbrg[4][128];                                  \
    __shared__ u16   s_rgbb[4][128];                                   \
    const int tid  = threadIdx.x;                                      \
    const int wv   = tid >> 6;                                         \
    const int lane = tid & 63;                                         \
    const int c16  = lane & 15;                                        \
    const int kg   = lane >> 4;                                        \
    const int ray  = blockIdx.x * 4 + wv;                              \
    const int sA   = c16 + 16 * ((2 * kg) & 3);                        \
    const int sB   = c16 + 16 * ((2 * kg + 1) & 3);                    \
    u16x8 AW2[2], AWc2[2];                                             \
    {                                                                  \
        const u16x8* wf = (const u16x8*)wsb;                           \
        _Pragma("unroll")                                              \
        for (int i = 0; i < 2; ++i)                                    \
            s_wfrag[tid + 256 * i] = wf[tid + 256 * i];                \
        _Pragma("unroll")                                              \
        for (int ks = 0; ks < 2; ++ks) {                               \
            AW2[ks]  = wf[512 + ks * 64 + lane];                       \
            AWc2[ks] = wf[640 + ks * 64 + lane];                       \
        }                                                              \
    }                                                                  \
    if (tid < 96) {                                                    \
        float v;                                                       \
        if (tid < 64)      v = b1[tid];                                \
        else if (tid < 80) v = b2[tid - 64];                           \
        else               v = (tid - 80 < 3) ? bc2[tid - 80] : 0.f;   \
        s_bias[tid] = v;                                               \
    }                                                                  \
    float ox = rays_o[ray * 3 + 0], oy = rays_o[ray * 3 + 1], oz = rays_o[ray * 3 + 2]; \
    float dx = rays_d[ray * 3 + 0], dy = rays_d[ray * 3 + 1], dz = rays_d[ray * 3 + 2]; \
    float rn = rsqrtf(dx * dx + dy * dy + dz * dz);                    \
    dx *= rn; dy *= rn; dz *= rn;                                      \
    float lo0 = aabb[0], lo1 = aabb[1], lo2 = aabb[2];                 \
    float hi0 = aabb[3], hi1 = aabb[4], hi2 = aabb[5];                 \
    float invx = 1.f / dx, invy = 1.f / dy, invz = 1.f / dz;           \
    float tx0 = (lo0 - ox) * invx, tx1 = (hi0 - ox) * invx;            \
    float ty0 = (lo1 - oy) * invy, ty1 = (hi1 - oy) * invy;            \
    float tz0 = (lo2 - oz) * invz, tz1 = (hi2 - oz) * invz;            \
    float tnear = fmaxf(fmaxf(fminf(tx0, tx1), fminf(ty0, ty1)), fminf(tz0, tz1)); \
    tnear = fmaxf(tnear, 0.f);                                         \
    float tfar = fminf(fminf(fmaxf(tx0, tx1), fmaxf(ty0, ty1)), fmaxf(tz0, tz1)); \
    tfar = fmaxf(tfar, tnear);                                         \
    float delta = (tfar - tnear) * (1.f / (float)NS);                  \
    const u32 dir01 = pk2bf(dx, dy);                                   \
    const u32 dir2b = pk2bf(dz, 1.0f);                                 \
    _Pragma("unroll")                                                  \
    for (int i = 0; i < 2; ++i) {                                      \
        int s = i * 64 + lane;                                         \
        float t = tnear + delta * ((float)s + 0.5f);                   \
        float px = ox + dx * t, py = oy + dy * t, pz = oz + dz * t;    \
        px = (px - lo0) * (2.f / (hi0 - lo0)) - 1.f;                   \
        py = (py - lo1) * (2.f / (hi1 - lo1)) - 1.f;                   \
        pz = (pz - lo2) * (2.f / (hi2 - lo2)) - 1.f;                   \
        float p01[3], p02[3], p12[3];                                  \
        plane_interp(plane01, px, py, p01);                            \
        plane_interp(plane02, px, pz, p02);                            \
        plane_interp(plane12, py, pz, p12);                            \
        float gx = p01[0] * p02[0] * p12[0];                           \
        float gy = p01[1] * p02[1] * p12[1];                           \
        float gz = p01[2] * p02[2] * p12[2];                           \
        float qx = clampf((gx + 1.f) * (0.5f * 63.f), 0.f, 63.f);      \
        float qy = clampf((gy + 1.f) * (0.5f * 63.f), 0.f, 63.f);      \
        float qz = clampf((gz + 1.f) * (0.5f * 63.f), 0.f, 63.f);      \
        int ixg = (int)qx; if (ixg > 62) ixg = 62;                     \
        int iyg = (int)qy; if (iyg > 62) iyg = 62;                     \
        int izg = (int)qz; if (izg > 62) izg = 62;                     \
        float fx = qx - (float)ixg, fy = qy - (float)iyg, fz = qz - (float)izg; \
        float wx0 = 1.f - fx, wy0 = 1.f - fy, wz0 = 1.f - fz;          \
        u32x4 cw;                                                      \
        cw[0] = pkh(wx0 * wy0 * wz0, wx0 * wy0 * fz);                  \
        cw[1] = pkh(wx0 * fy  * wz0, wx0 * fy  * fz);                  \
        cw[2] = pkh(fx  * wy0 * wz0, fx  * wy0 * fz);                  \
        cw[3] = pkh(fx  * fy  * wz0, fx  * fy  * fz);                  \
        s_cw[wv][s] = cw;                                              \
        s_fb[wv][s] = (u32)(ixg * 4096 + iyg * 64 + izg);              \
    }                                                                  \
    __syncthreads();                                                   \
    _Pragma("unroll 1")                                                \
    for (int c = 0; c < 8; ++c) {                                      \
        u32x4 cwp = s_cw[wv][c * 16 + c16];                            \
        u32 vidx = s_fb[wv][c * 16 + c16];                             \
        f32x2 w0v = uph2(cwp[0]);                                      \
        f32x2 w1v = uph2(cwp[1]);                                      \
        f32x2 w2v = uph2(cwp[2]);                                      \
        f32x2 w3v = uph2(cwp[3]);                                      \
        u32x4 a1v;                                                     \
        { __VA_ARGS__ }                                                \
        u16x8 a1 = __builtin_bit_cast(u16x8, a1v);                     \
        {                                                              \
            f32x4 g0 = mfma_bf16(s_wfrag[0 * 64 + lane], a1, *(const f32x4*)&s_bias[0 * 16 + kg * 4]); \
            f32x4 g1 = mfma_bf16(s_wfrag[1 * 64 + lane], a1, *(const f32x4*)&s_bias[1 * 16 + kg * 4]); \
            RELUSTORE(g0, 0); RELUSTORE(g1, 1);                        \
        }                                                              \
        {                                                              \
            f32x4 g2 = mfma_bf16(s_wfrag[2 * 64 + lane], a1, *(const f32x4*)&s_bias[2 * 16 + kg * 4]); \
            f32x4 g3 = mfma_bf16(s_wfrag[3 * 64 + lane], a1, *(const f32x4*)&s_bias[3 * 16 + kg * 4]); \
            RELUSTORE(g2, 2); RELUSTORE(g3, 3);                        \
        }                                                              \
        u16x8 B2_0 = *(const u16x8*)&s_tile[wv][TSW(c16, kg * 8)];     \
        u16x8 B2_1 = *(const u16x8*)&s_tile[wv][TSW(c16, 32 + kg * 8)];\
        f32x4 so = mfma_bf16(AW2[0], B2_0, *(const f32x4*)&s_bias[64 + kg * 4]); \
        so = mfma_bf16(AW2[1], B2_1, so);                              \
        if (kg == 0) {                                                 \
            float dens = __expf(clampf(so[0], -15.f, 15.f));           \
            s_tau[wv][c * 16 + c16] = dens * delta;                    \
        }                                                              \
        u32 Q0 = pk2bf(so[0], so[1]);                                  \
        u32 Q1 = pk2bf(so[2], so[3]);                                  \
        u32x4 ct;                                                      \
        ct[0] = (u32)__shfl((int)Q0, sA);                              \
        ct[1] = (u32)__shfl((int)Q1, sA);                              \
        ct[2] = (u32)__shfl((int)Q0, sB);                              \
        ct[3] = (u32)__shfl((int)Q1, sB);                              \
        if (kg == 2) { ct[0] = dir01; ct[1] = dir2b; ct[2] = 0u; ct[3] = 0u; } \
        if (kg == 3) { ct[0] = 0u; ct[1] = 0u; ct[2] = 0u; ct[3] = 0u; } \
        u16x8 bcin = __builtin_bit_cast(u16x8, ct);                    \
        {                                                              \
            f32x4 zz; zz[0] = zz[1] = zz[2] = zz[3] = 0.f;             \
            f32x4 h0 = mfma_bf16(s_wfrag[256 + 0 * 64 + lane], bcin, zz); \
            f32x4 h1 = mfma_bf16(s_wfrag[256 + 1 * 64 + lane], bcin, zz); \
            RELUSTORE(h0, 0); RELUSTORE(h1, 1);                        \
        }                                                              \
        {                                                              \
            f32x4 zz; zz[0] = zz[1] = zz[2] = zz[3] = 0.f;             \
            f32x4 h2 = mfma_bf16(s_wfrag[256 + 2 * 64 + lane], bcin, zz); \
            f32x4 h3 = mfma_bf16(s_wfrag[256 + 3 * 64 + lane], bcin, zz); \
            RELUSTORE(h2, 2); RELUSTORE(h3, 3);                        \
        }                                                              \
        u16x8 B4_0 = *(const u16x8*)&s_tile[wv][TSW(c16, kg * 8)];     \
        u16x8 B4_1 = *(const u16x8*)&s_tile[wv][TSW(c16, 32 + kg * 8)];\
        f32x4 cacc = mfma_bf16(AWc2[0], B4_0, *(const f32x4*)&s_bias[80 + kg * 4]); \
        cacc = mfma_bf16(AWc2[1], B4_1, cacc);                         \
        if (kg == 0) {                                                 \
            int si = c * 16 + c16;                                     \
            float r = 1.f / (1.f + __expf(-cacc[0]));                  \
            float g = 1.f / (1.f + __expf(-cacc[1]));                  \
            float b = 1.f / (1.f + __expf(-cacc[2]));                  \
            s_rgbrg[wv][si] = pkh(r, g);                               \
            s_rgbb[wv][si] = (u16)(pkh(b, 0.f) & 0xffffu);             \
        }                                                              \
    }                                                                  \
    float t0 = s_tau[wv][lane];                                        \
    float t1 = s_tau[wv][64 + lane];                                   \
    float x0 = t0, x1 = t1;                                            \
    _Pragma("unroll")                                                  \
    for (int off = 1; off < 64; off <<= 1) {                           \
        float y = __shfl_up(x0, off);                                  \
        if (lane >= off) x0 += y;                                      \
    }                                                                  \
    float tot0 = __shfl(x0, 63);                                       \
    _Pragma("unroll")                                                  \
    for (int off = 1; off < 64; off <<= 1) {                           \
        float y = __shfl_up(x1, off);                                  \
        if (lane >= off) x1 += y;                                      \
    }                                                                  \
    x1 += tot0;                                                        \
    float w0 = __expf(t0 - x0) * (1.f - __expf(-t0));                  \
    float w1s = __expf(t1 - x1) * (1.f - __expf(-t1));                 \
    float2 rg0 = uph(s_rgbrg[wv][lane]);                               \
    float2 rg1 = uph(s_rgbrg[wv][64 + lane]);                          \
    float bb0 = uph((u32)s_rgbb[wv][lane]).x;                          \
    float bb1 = uph((u32)s_rgbb[wv][64 + lane]).x;                     \
    float v0 = w0 * rg0.x + w1s * rg1.x;                               \
    float v1 = w0 * rg0.y + w1s * rg1.y;                               \
    float v2 = w0 * bb0 + w1s * bb1;                                   \
    float v3 = w0 + w1s;                                               \
    _Pragma("unroll")                                                  \
    for (int off = 32; off; off >>= 1) {                               \
        v0 += __shfl_xor(v0, off);                                     \
        v1 += __shfl_xor(v1, off);                                     \
        v2 += __shfl_xor(v2, off);                                     \
        v3 += __shfl_xor(v3, off);                                     \
    }                                                                  \
    if (lane == 0) {                                                   \
        float bg = bg_color[0];                                        \
        out[ray * 3 + 0] = v0 + (1.f - v3) * bg;                       \
        out[ray * 3 + 1] = v1 + (1.f - v3) * bg;                       \
        out[ray * 3 + 2] = v2 + (1.f - v3) * bg;                       \
    }

// ---- HOT kernel: bf16 channel-last grid gather ----
__global__ __launch_bounds__(256)
void nerf_mfma_grid(const float* __restrict__ rays_o,
                    const float* __restrict__ rays_d,
                    const float* __restrict__ bg_color,
                    const float* __restrict__ plane01,
                    const float* __restrict__ plane02,
                    const float* __restrict__ plane12,
                    const float* __restrict__ b1, const float* __restrict__ b2,
                    const float* __restrict__ bc2,
                    const float* __restrict__ aabb,
                    float* __restrict__ out,
                    const u16* __restrict__ wsb,
                    const u16* __restrict__ wsg)
{
    const char* gby = (const char*)wsg;
    KERNEL_BODY(
        u32 o0  = vidx * 64u + (u32)(kg * 16);
        u32 oy  = o0 + 4096u;
        u32 ox  = o0 + 262144u;
        u32 oxy = o0 + 266240u;
        u32x4 q00 = *(const u32x4*)(gby + o0);
        u32x4 q01 = *(const u32x4*)(gby + o0 + 64);
        u32x4 q10 = *(const u32x4*)(gby + oy);
        u32x4 q11 = *(const u32x4*)(gby + oy + 64);
        u32x4 q20 = *(const u32x4*)(gby + ox);
        u32x4 q21 = *(const u32x4*)(gby + ox + 64);
        u32x4 q30 = *(const u32x4*)(gby + oxy);
        u32x4 q31 = *(const u32x4*)(gby + oxy + 64);
        f32x2 p0, p1, p2, p3;
        p0[0] = p0[1] = 0.f; p1 = p0; p2 = p0; p3 = p0;
        CORNER(q00, w0v[0]); CORNER(q01, w0v[1]);
        CORNER(q10, w1v[0]); CORNER(q11, w1v[1]);
        CORNER(q20, w2v[0]); CORNER(q21, w2v[1]);
        CORNER(q30, w3v[0]); CORNER(q31, w3v[1]);
        a1v[0] = pk2bf(p0[0], p0[1]);
        a1v[1] = pk2bf(p1[0], p1[1]);
        a1v[2] = pk2bf(p2[0], p2[1]);
        a1v[3] = pk2bf(p3[0], p3[1]);
    )
}

// ---- fallback kernel: planar f32 gather ----
__global__ __launch_bounds__(256)
void nerf_mfma_planar(const float* __restrict__ rays_o,
                      const float* __restrict__ rays_d,
                      const float* __restrict__ bg_color,
                      const float* __restrict__ plane01,
                      const float* __restrict__ plane02,
                      const float* __restrict__ plane12,
                      const float* __restrict__ b1, const float* __restrict__ b2,
                      const float* __restrict__ bc2,
                      const float* __restrict__ aabb,
                      float* __restrict__ out,
                      const u16* __restrict__ wsb,
                      const float* __restrict__ features)
{
    const char* fby  = (const char*)features;
    const char* fby2 = fby + 16384;
    KERNEL_BODY(
        u32 chb = vidx * 4u + (u32)(kg * 8) * 1048576u;
        _Pragma("unroll")
        for (int jj = 0; jj < 4; ++jj) {
            float vv[2];
            _Pragma("unroll")
            for (int h = 0; h < 2; ++h) {
                u32 off = chb + (u32)(jj * 2 + h) * 1048576u;
                f32x2 q0 = *(const f32x2u*)(fby + off);
                f32x2 q1 = *(const f32x2u*)(fby + off + 256);
                f32x2 q2 = *(const f32x2u*)(fby2 + off);
                f32x2 q3 = *(const f32x2u*)(fby2 + off + 256);
                f32x2 acc = q0 * w0v;
                acc = __builtin_elementwise_fma(q1, w1v, acc);
                acc = __builtin_elementwise_fma(q2, w2v, acc);
                acc = __builtin_elementwise_fma(q3, w3v, acc);
                vv[h] = acc[0] + acc[1];
            }
            a1v[jj] = pk2bf(vv[0], vv[1]);
        }
    )
}

extern "C" void kernel_launch(void* const* d_in, const int* in_sizes, int n_in,
                              void* d_out, int out_size, void* d_ws, size_t ws_size,
                              hipStream_t stream) {
    const float* rays_o  = (const float*)d_in[0];
    const float* rays_d  = (const float*)d_in[1];
    const float* bg      = (const float*)d_in[2];
    const float* p01     = (const float*)d_in[3];
    const float* p02     = (const float*)d_in[4];
    const float* p12     = (const float*)d_in[5];
    const float* feats   = (const float*)d_in[6];
    const float* w1      = (const float*)d_in[7];
    const float* b1      = (const float*)d_in[8];
    const float* w2      = (const float*)d_in[9];
    const float* b2      = (const float*)d_in[10];
    const float* wc1     = (const float*)d_in[11];
    const float* bc1     = (const float*)d_in[12];
    const float* wc2     = (const float*)d_in[13];
    const float* bc2     = (const float*)d_in[14];
    const float* aabb    = (const float*)d_in[15];
    float* out = (float*)d_out;

    const int use_grid = (ws_size >= (size_t)GRID16_BYTES + WSB_BYTES) ? 1 : 0;

    if (use_grid) {
        u16* wsg16 = (u16*)d_ws;
        u16* wsb = (u16*)((char*)d_ws + GRID16_BYTES);
        prep_all<<<1048, 256, 0, stream>>>(feats, wsg16, w1, wc1, w2, wc2, bc1, wsb);
        nerf_mfma_grid<<<NRAYS / 4, 256, 0, stream>>>(
            rays_o, rays_d, bg, p01, p02, p12, b1, b2, bc2, aabb, out, wsb, wsg16);
    } else {
        u16* wsb = (u16*)d_ws;
        prep_weights<<<24, 256, 0, stream>>>(w1, wc1, w2, wc2, bc1, wsb);
        nerf_mfma_planar<<<NRAYS / 4, 256, 0, stream>>>(
            rays_o, rays_d, bg, p01, p02, p12, b1, b2, bc2, aabb, out, wsb, feats);
    }
}

// Round 22
// 61.536 us; speedup vs baseline: 1.5252x; 1.2461x over previous
//
#include <hip/hip_runtime.h>

#define NS 128
#define NRAYS 8192
#define GRID16_BYTES 16777216u   // 262144 voxels * 32 ch * 2 B
#define WSB_BYTES 12288u

typedef unsigned short u16;
typedef unsigned int   u32;
typedef unsigned short u16x8 __attribute__((ext_vector_type(8)));
typedef _Float16 h16x8 __attribute__((ext_vector_type(8)));
typedef float f32x4 __attribute__((ext_vector_type(4)));
typedef float f32x2 __attribute__((ext_vector_type(2)));
typedef _Float16 h16x2 __attribute__((ext_vector_type(2)));
typedef unsigned int u32x4 __attribute__((ext_vector_type(4)));
typedef unsigned int u32x2 __attribute__((ext_vector_type(2)));
typedef float f32x2u __attribute__((ext_vector_type(2), aligned(4)));

__device__ __forceinline__ float clampf(float x, float lo, float hi) {
    return fminf(fmaxf(x, lo), hi);
}

// f32 -> f16 bits
__device__ __forceinline__ u16 f2h(float f) {
    return __builtin_bit_cast(u16, (_Float16)f);
}
// pack two f32 -> f16x2 dword (v_cvt_pkrtz_f16_f32: single instruction)
__device__ __forceinline__ u32 pkh(float a, float b) {
    h16x2 v; v[0] = (_Float16)a; v[1] = (_Float16)b;
    return __builtin_bit_cast(u32, v);
}
__device__ __forceinline__ float2 uph(u32 u) {
    h16x2 v = __builtin_bit_cast(h16x2, u);
    return make_float2((float)v[0], (float)v[1]);
}
__device__ __forceinline__ f32x2 uph2(u32 u) {
    h16x2 v = __builtin_bit_cast(h16x2, u);
    f32x2 r; r[0] = (float)v[0]; r[1] = (float)v[1];
    return r;
}

__device__ __forceinline__ f32x4 mfma_f16(u16x8 a, u16x8 b, f32x4 c) {
    return __builtin_amdgcn_mfma_f32_16x16x32_f16(
        __builtin_bit_cast(h16x8, a), __builtin_bit_cast(h16x8, b), c, 0, 0, 0);
}

#define TSW(n, k) ((((n) * 64) + (k)) ^ (((n) & 7) << 3))

__device__ __forceinline__ void plane_interp(const float* __restrict__ g,
                                             float ca, float cb, float o[3]) {
    float pa = clampf((ca + 1.f) * (0.5f * 127.f), 0.f, 127.f);
    float pb = clampf((cb + 1.f) * (0.5f * 127.f), 0.f, 127.f);
    int la = (int)pa; if (la > 126) la = 126;
    int lb = (int)pb; if (lb > 126) lb = 126;
    float fa = pa - (float)la, fb = pb - (float)lb;
    const float* p = g + la * 128 + lb;
#pragma unroll
    for (int c = 0; c < 3; ++c) {
        const float* q = p + c * 16384;
        f32x2u q0 = *(const f32x2u*)q;
        f32x2u q1 = *(const f32x2u*)(q + 128);
        float top = fmaf(q0[1] - q0[0], fb, q0[0]);
        float bot = fmaf(q1[1] - q1[0], fb, q1[0]);
        o[c] = fmaf(bot - top, fa, top);
    }
}

__device__ __forceinline__ void weight_pack_item(
    int idx, const float* __restrict__ w1, const float* __restrict__ wc1,
    const float* __restrict__ w2, const float* __restrict__ wc2,
    const float* __restrict__ bc1, u16* __restrict__ wsb)
{
    int lane = (idx >> 3) & 63;
    int j = idx & 7;
    int c16 = lane & 15, kg = lane >> 4;
    float v;
    if (idx < 2048) {
        int nb = idx >> 9;
        int k = kg * 8 + j;
        v = w1[k * 64 + nb * 16 + c16];
    } else if (idx < 4096) {
        int nb = (idx - 2048) >> 9;
        int k = kg * 8 + j;
        if (k == 0)       v = 0.f;
        else if (k < 16)  v = wc1[(k + 2) * 64 + nb * 16 + c16];
        else if (k < 19)  v = wc1[(k - 16) * 64 + nb * 16 + c16];
        else if (k == 19) v = bc1[nb * 16 + c16];
        else              v = 0.f;
    } else if (idx < 5120) {
        int ks = (idx - 4096) >> 9;
        int k = ks * 32 + kg * 8 + j;
        v = w2[k * 16 + c16];
    } else {
        int ks = (idx - 5120) >> 9;
        int k = ks * 32 + kg * 8 + j;
        v = (c16 < 3) ? wc2[k * 3 + c16] : 0.f;
    }
    wsb[idx] = f2h(v);
}

// ---- merged prep: blocks 0..1023 repack grid to f16 channel-last;
//      blocks 1024..1047 pack weight A-fragments (f16) ----
__global__ __launch_bounds__(256)
void prep_all(const float* __restrict__ f, u16* __restrict__ g16,
              const float* __restrict__ w1, const float* __restrict__ wc1,
              const float* __restrict__ w2, const float* __restrict__ wc2,
              const float* __restrict__ bc1, u16* __restrict__ wsb)
{
    int bid = blockIdx.x;
    if (bid < 1024) {
        int vox = bid * 256 + threadIdx.x;
        u32 acc[16];
#pragma unroll
        for (int c = 0; c < 32; c += 2) {
            float a = f[(size_t)c * 262144 + vox];
            float b = f[(size_t)(c + 1) * 262144 + vox];
            acc[c >> 1] = pkh(a, b);
        }
        u32x4* o = (u32x4*)(g16 + (size_t)vox * 32);
#pragma unroll
        for (int k = 0; k < 4; ++k) {
            u32x4 w; w[0] = acc[k * 4]; w[1] = acc[k * 4 + 1];
            w[2] = acc[k * 4 + 2]; w[3] = acc[k * 4 + 3];
            o[k] = w;
        }
    } else {
        int idx = (bid - 1024) * 256 + threadIdx.x;
        if (idx < 6144) weight_pack_item(idx, w1, wc1, w2, wc2, bc1, wsb);
    }
}

// ---- standalone weight prep (tiny-ws fallback) ----
__global__ __launch_bounds__(256)
void prep_weights(const float* __restrict__ w1, const float* __restrict__ wc1,
                  const float* __restrict__ w2, const float* __restrict__ wc2,
                  const float* __restrict__ bc1, u16* __restrict__ wsb)
{
    int idx = blockIdx.x * 256 + threadIdx.x;
    if (idx < 6144) weight_pack_item(idx, w1, wc1, w2, wc2, bc1, wsb);
}

// relu (packed f32) then single-instruction packed f32->f16 converts
#define RELUSTORE(ACC, NB) {                                           \
        f32x2 lo_; lo_[0] = (ACC)[0]; lo_[1] = (ACC)[1];               \
        f32x2 hi_; hi_[0] = (ACC)[2]; hi_[1] = (ACC)[3];               \
        f32x2 z2_; z2_[0] = 0.f; z2_[1] = 0.f;                         \
        lo_ = __builtin_elementwise_max(lo_, z2_);                     \
        hi_ = __builtin_elementwise_max(hi_, z2_);                     \
        u32x2 wr_;                                                     \
        wr_[0] = pkh(lo_[0], lo_[1]);                                  \
        wr_[1] = pkh(hi_[0], hi_[1]);                                  \
        *(u32x2*)&s_tile[wv][TSW(c16, (NB) * 16 + kg * 4)] = wr_; }

// f16 packed corner accumulate: acc(h16x2 x4) += Q(h16x2 words) * splat(W)
#define CORNERH(Q, WS) {                                               \
        p0 = __builtin_elementwise_fma(__builtin_bit_cast(h16x2, (Q)[0]), WS, p0); \
        p1 = __builtin_elementwise_fma(__builtin_bit_cast(h16x2, (Q)[1]), WS, p1); \
        p2 = __builtin_elementwise_fma(__builtin_bit_cast(h16x2, (Q)[2]), WS, p2); \
        p3 = __builtin_elementwise_fma(__builtin_bit_cast(h16x2, (Q)[3]), WS, p3); }

// shared prologue/epilogue; VARIADIC so commas inside the gather block are safe
#define KERNEL_BODY(...)                                               \
    __shared__ __align__(16) u16x8 s_wfrag[512];                       \
    __shared__ __align__(16) float s_bias[96];                         \
    __shared__ __align__(16) u32x4 s_cw[4][128];                       \
    __shared__ u32   s_fb[4][128];                                     \
    __shared__ __align__(16) u16  s_tile[4][16 * 64];                  \
    __shared__ float s_tau[4][128];                                    \
    __shared__ u32   s_rgbrg[4][128];                                  \
    __shared__ u16   s_rgbb[4][128];                                   \
    const int tid  = threadIdx.x;                                      \
    const int wv   = tid >> 6;                                         \
    const int lane = tid & 63;                                         \
    const int c16  = lane & 15;                                        \
    const int kg   = lane >> 4;                                        \
    const int ray  = blockIdx.x * 4 + wv;                              \
    const int sA   = c16 + 16 * ((2 * kg) & 3);                        \
    const int sB   = c16 + 16 * ((2 * kg + 1) & 3);                    \
    u16x8 AW2[2], AWc2[2];                                             \
    {                                                                  \
        const u16x8* wf = (const u16x8*)wsb;                           \
        _Pragma("unroll")                                              \
        for (int i = 0; i < 2; ++i)                                    \
            s_wfrag[tid + 256 * i] = wf[tid + 256 * i];                \
        _Pragma("unroll")                                              \
        for (int ks = 0; ks < 2; ++ks) {                               \
            AW2[ks]  = wf[512 + ks * 64 + lane];                       \
            AWc2[ks] = wf[640 + ks * 64 + lane];                       \
        }                                                              \
    }                                                                  \
    if (tid < 96) {                                                    \
        float v;                                                       \
        if (tid < 64)      v = b1[tid];                                \
        else if (tid < 80) v = b2[tid - 64];                           \
        else               v = (tid - 80 < 3) ? bc2[tid - 80] : 0.f;   \
        s_bias[tid] = v;                                               \
    }                                                                  \
    float ox = rays_o[ray * 3 + 0], oy = rays_o[ray * 3 + 1], oz = rays_o[ray * 3 + 2]; \
    float dx = rays_d[ray * 3 + 0], dy = rays_d[ray * 3 + 1], dz = rays_d[ray * 3 + 2]; \
    float rn = rsqrtf(dx * dx + dy * dy + dz * dz);                    \
    dx *= rn; dy *= rn; dz *= rn;                                      \
    float lo0 = aabb[0], lo1 = aabb[1], lo2 = aabb[2];                 \
    float hi0 = aabb[3], hi1 = aabb[4], hi2 = aabb[5];                 \
    float invx = 1.f / dx, invy = 1.f / dy, invz = 1.f / dz;           \
    float tx0 = (lo0 - ox) * invx, tx1 = (hi0 - ox) * invx;            \
    float ty0 = (lo1 - oy) * invy, ty1 = (hi1 - oy) * invy;            \
    float tz0 = (lo2 - oz) * invz, tz1 = (hi2 - oz) * invz;            \
    float tnear = fmaxf(fmaxf(fminf(tx0, tx1), fminf(ty0, ty1)), fminf(tz0, tz1)); \
    tnear = fmaxf(tnear, 0.f);                                         \
    float tfar = fminf(fminf(fmaxf(tx0, tx1), fmaxf(ty0, ty1)), fmaxf(tz0, tz1)); \
    tfar = fmaxf(tfar, tnear);                                         \
    float delta = (tfar - tnear) * (1.f / (float)NS);                  \
    const u32 dir01 = pkh(dx, dy);                                     \
    const u32 dir2b = pkh(dz, 1.0f);                                   \
    _Pragma("unroll")                                                  \
    for (int i = 0; i < 2; ++i) {                                      \
        int s = i * 64 + lane;                                         \
        float t = tnear + delta * ((float)s + 0.5f);                   \
        float px = ox + dx * t, py = oy + dy * t, pz = oz + dz * t;    \
        px = (px - lo0) * (2.f / (hi0 - lo0)) - 1.f;                   \
        py = (py - lo1) * (2.f / (hi1 - lo1)) - 1.f;                   \
        pz = (pz - lo2) * (2.f / (hi2 - lo2)) - 1.f;                   \
        float p01[3], p02[3], p12[3];                                  \
        plane_interp(plane01, px, py, p01);                            \
        plane_interp(plane02, px, pz, p02);                            \
        plane_interp(plane12, py, pz, p12);                            \
        float gx = p01[0] * p02[0] * p12[0];                           \
        float gy = p01[1] * p02[1] * p12[1];                           \
        float gz = p01[2] * p02[2] * p12[2];                           \
        float qx = clampf((gx + 1.f) * (0.5f * 63.f), 0.f, 63.f);      \
        float qy = clampf((gy + 1.f) * (0.5f * 63.f), 0.f, 63.f);      \
        float qz = clampf((gz + 1.f) * (0.5f * 63.f), 0.f, 63.f);      \
        int ixg = (int)qx; if (ixg > 62) ixg = 62;                     \
        int iyg = (int)qy; if (iyg > 62) iyg = 62;                     \
        int izg = (int)qz; if (izg > 62) izg = 62;                     \
        float fx = qx - (float)ixg, fy = qy - (float)iyg, fz = qz - (float)izg; \
        float wx0 = 1.f - fx, wy0 = 1.f - fy, wz0 = 1.f - fz;          \
        u32x4 cw;                                                      \
        cw[0] = pkh(wx0 * wy0 * wz0, wx0 * wy0 * fz);                  \
        cw[1] = pkh(wx0 * fy  * wz0, wx0 * fy  * fz);                  \
        cw[2] = pkh(fx  * wy0 * wz0, fx  * wy0 * fz);                  \
        cw[3] = pkh(fx  * fy  * wz0, fx  * fy  * fz);                  \
        s_cw[wv][s] = cw;                                              \
        s_fb[wv][s] = (u32)(ixg * 4096 + iyg * 64 + izg);              \
    }                                                                  \
    __syncthreads();                                                   \
    _Pragma("unroll 1")                                                \
    for (int c = 0; c < 8; ++c) {                                      \
        u32x4 cwp = s_cw[wv][c * 16 + c16];                            \
        u32 vidx = s_fb[wv][c * 16 + c16];                             \
        u32x4 a1v;                                                     \
        { __VA_ARGS__ }                                                \
        u16x8 a1 = __builtin_bit_cast(u16x8, a1v);                     \
        f32x4 g0 = mfma_f16(s_wfrag[0 * 64 + lane], a1, *(const f32x4*)&s_bias[0 * 16 + kg * 4]); \
        f32x4 g1 = mfma_f16(s_wfrag[1 * 64 + lane], a1, *(const f32x4*)&s_bias[1 * 16 + kg * 4]); \
        f32x4 g2 = mfma_f16(s_wfrag[2 * 64 + lane], a1, *(const f32x4*)&s_bias[2 * 16 + kg * 4]); \
        f32x4 g3 = mfma_f16(s_wfrag[3 * 64 + lane], a1, *(const f32x4*)&s_bias[3 * 16 + kg * 4]); \
        RELUSTORE(g0, 0); RELUSTORE(g1, 1); RELUSTORE(g2, 2); RELUSTORE(g3, 3); \
        u16x8 B2_0 = *(const u16x8*)&s_tile[wv][TSW(c16, kg * 8)];     \
        u16x8 B2_1 = *(const u16x8*)&s_tile[wv][TSW(c16, 32 + kg * 8)];\
        f32x4 so = mfma_f16(AW2[0], B2_0, *(const f32x4*)&s_bias[64 + kg * 4]); \
        so = mfma_f16(AW2[1], B2_1, so);                               \
        if (kg == 0) {                                                 \
            float dens = __expf(clampf(so[0], -15.f, 15.f));           \
            s_tau[wv][c * 16 + c16] = dens * delta;                    \
        }                                                              \
        u32 Q0 = pkh(so[0], so[1]);                                    \
        u32 Q1 = pkh(so[2], so[3]);                                    \
        u32x4 ct;                                                      \
        ct[0] = (u32)__shfl((int)Q0, sA);                              \
        ct[1] = (u32)__shfl((int)Q1, sA);                              \
        ct[2] = (u32)__shfl((int)Q0, sB);                              \
        ct[3] = (u32)__shfl((int)Q1, sB);                              \
        if (kg == 2) { ct[0] = dir01; ct[1] = dir2b; ct[2] = 0u; ct[3] = 0u; } \
        if (kg == 3) { ct[0] = 0u; ct[1] = 0u; ct[2] = 0u; ct[3] = 0u; } \
        u16x8 bcin = __builtin_bit_cast(u16x8, ct);                    \
        f32x4 zz; zz[0] = zz[1] = zz[2] = zz[3] = 0.f;                 \
        f32x4 h0 = mfma_f16(s_wfrag[256 + 0 * 64 + lane], bcin, zz);   \
        f32x4 h1 = mfma_f16(s_wfrag[256 + 1 * 64 + lane], bcin, zz);   \
        f32x4 h2 = mfma_f16(s_wfrag[256 + 2 * 64 + lane], bcin, zz);   \
        f32x4 h3 = mfma_f16(s_wfrag[256 + 3 * 64 + lane], bcin, zz);   \
        RELUSTORE(h0, 0); RELUSTORE(h1, 1); RELUSTORE(h2, 2); RELUSTORE(h3, 3); \
        u16x8 B4_0 = *(const u16x8*)&s_tile[wv][TSW(c16, kg * 8)];     \
        u16x8 B4_1 = *(const u16x8*)&s_tile[wv][TSW(c16, 32 + kg * 8)];\
        f32x4 cacc = mfma_f16(AWc2[0], B4_0, *(const f32x4*)&s_bias[80 + kg * 4]); \
        cacc = mfma_f16(AWc2[1], B4_1, cacc);                          \
        if (kg == 0) {                                                 \
            int si = c * 16 + c16;                                     \
            float r = 1.f / (1.f + __expf(-cacc[0]));                  \
            float g = 1.f / (1.f + __expf(-cacc[1]));                  \
            float b = 1.f / (1.f + __expf(-cacc[2]));                  \
            s_rgbrg[wv][si] = pkh(r, g);                               \
            s_rgbb[wv][si] = (u16)(pkh(b, 0.f) & 0xffffu);             \
        }                                                              \
    }                                                                  \
    float t0 = s_tau[wv][lane];                                        \
    float t1 = s_tau[wv][64 + lane];                                   \
    float x0 = t0, x1 = t1;                                            \
    _Pragma("unroll")                                                  \
    for (int off = 1; off < 64; off <<= 1) {                           \
        float y = __shfl_up(x0, off);                                  \
        if (lane >= off) x0 += y;                                      \
    }                                                                  \
    float tot0 = __shfl(x0, 63);                                       \
    _Pragma("unroll")                                                  \
    for (int off = 1; off < 64; off <<= 1) {                           \
        float y = __shfl_up(x1, off);                                  \
        if (lane >= off) x1 += y;                                      \
    }                                                                  \
    x1 += tot0;                                                        \
    float w0 = __expf(t0 - x0) * (1.f - __expf(-t0));                  \
    float w1s = __expf(t1 - x1) * (1.f - __expf(-t1));                 \
    float2 rg0 = uph(s_rgbrg[wv][lane]);                               \
    float2 rg1 = uph(s_rgbrg[wv][64 + lane]);                          \
    float bb0 = uph((u32)s_rgbb[wv][lane]).x;                          \
    float bb1 = uph((u32)s_rgbb[wv][64 + lane]).x;                     \
    float v0 = w0 * rg0.x + w1s * rg1.x;                               \
    float v1 = w0 * rg0.y + w1s * rg1.y;                               \
    float v2 = w0 * bb0 + w1s * bb1;                                   \
    float v3 = w0 + w1s;                                               \
    _Pragma("unroll")                                                  \
    for (int off = 32; off; off >>= 1) {                               \
        v0 += __shfl_xor(v0, off);                                     \
        v1 += __shfl_xor(v1, off);                                     \
        v2 += __shfl_xor(v2, off);                                     \
        v3 += __shfl_xor(v3, off);                                     \
    }                                                                  \
    if (lane == 0) {                                                   \
        float bg = bg_color[0];                                        \
        out[ray * 3 + 0] = v0 + (1.f - v3) * bg;                       \
        out[ray * 3 + 1] = v1 + (1.f - v3) * bg;                       \
        out[ray * 3 + 2] = v2 + (1.f - v3) * bg;                       \
    }

// ---- HOT kernel: f16 channel-last grid gather, packed-f16 combine ----
__global__ __launch_bounds__(256)
void nerf_mfma_grid(const float* __restrict__ rays_o,
                    const float* __restrict__ rays_d,
                    const float* __restrict__ bg_color,
                    const float* __restrict__ plane01,
                    const float* __restrict__ plane02,
                    const float* __restrict__ plane12,
                    const float* __restrict__ b1, const float* __restrict__ b2,
                    const float* __restrict__ bc2,
                    const float* __restrict__ aabb,
                    float* __restrict__ out,
                    const u16* __restrict__ wsb,
                    const u16* __restrict__ wsg)
{
    const char* gby = (const char*)wsg;
    KERNEL_BODY(
        u32 o0  = vidx * 64u + (u32)(kg * 16);
        u32 oy  = o0 + 4096u;
        u32 ox  = o0 + 262144u;
        u32 oxy = o0 + 266240u;
        u32x4 q00 = *(const u32x4*)(gby + o0);
        u32x4 q01 = *(const u32x4*)(gby + o0 + 64);
        u32x4 q10 = *(const u32x4*)(gby + oy);
        u32x4 q11 = *(const u32x4*)(gby + oy + 64);
        u32x4 q20 = *(const u32x4*)(gby + ox);
        u32x4 q21 = *(const u32x4*)(gby + ox + 64);
        u32x4 q30 = *(const u32x4*)(gby + oxy);
        u32x4 q31 = *(const u32x4*)(gby + oxy + 64);
        h16x2 cwA = __builtin_bit_cast(h16x2, cwp[0]);
        h16x2 cwB = __builtin_bit_cast(h16x2, cwp[1]);
        h16x2 cwC = __builtin_bit_cast(h16x2, cwp[2]);
        h16x2 cwD = __builtin_bit_cast(h16x2, cwp[3]);
        h16x2 s00; s00[0] = cwA[0]; s00[1] = cwA[0];
        h16x2 s01; s01[0] = cwA[1]; s01[1] = cwA[1];
        h16x2 s10; s10[0] = cwB[0]; s10[1] = cwB[0];
        h16x2 s11; s11[0] = cwB[1]; s11[1] = cwB[1];
        h16x2 s20; s20[0] = cwC[0]; s20[1] = cwC[0];
        h16x2 s21; s21[0] = cwC[1]; s21[1] = cwC[1];
        h16x2 s30; s30[0] = cwD[0]; s30[1] = cwD[0];
        h16x2 s31; s31[0] = cwD[1]; s31[1] = cwD[1];
        h16x2 p0; p0[0] = (_Float16)0.f; p0[1] = (_Float16)0.f;
        h16x2 p1 = p0, p2 = p0, p3 = p0;
        CORNERH(q00, s00); CORNERH(q01, s01);
        CORNERH(q10, s10); CORNERH(q11, s11);
        CORNERH(q20, s20); CORNERH(q21, s21);
        CORNERH(q30, s30); CORNERH(q31, s31);
        a1v[0] = __builtin_bit_cast(u32, p0);
        a1v[1] = __builtin_bit_cast(u32, p1);
        a1v[2] = __builtin_bit_cast(u32, p2);
        a1v[3] = __builtin_bit_cast(u32, p3);
    )
}

// ---- fallback kernel: planar f32 gather (f16 output fragments) ----
__global__ __launch_bounds__(256)
void nerf_mfma_planar(const float* __restrict__ rays_o,
                      const float* __restrict__ rays_d,
                      const float* __restrict__ bg_color,
                      const float* __restrict__ plane01,
                      const float* __restrict__ plane02,
                      const float* __restrict__ plane12,
                      const float* __restrict__ b1, const float* __restrict__ b2,
                      const float* __restrict__ bc2,
                      const float* __restrict__ aabb,
                      float* __restrict__ out,
                      const u16* __restrict__ wsb,
                      const float* __restrict__ features)
{
    const char* fby  = (const char*)features;
    const char* fby2 = fby + 16384;
    KERNEL_BODY(
        f32x2 w0v = uph2(cwp[0]);
        f32x2 w1v = uph2(cwp[1]);
        f32x2 w2v = uph2(cwp[2]);
        f32x2 w3v = uph2(cwp[3]);
        u32 chb = vidx * 4u + (u32)(kg * 8) * 1048576u;
        _Pragma("unroll")
        for (int jj = 0; jj < 4; ++jj) {
            float vv[2];
            _Pragma("unroll")
            for (int h = 0; h < 2; ++h) {
                u32 off = chb + (u32)(jj * 2 + h) * 1048576u;
                f32x2 q0 = *(const f32x2u*)(fby + off);
                f32x2 q1 = *(const f32x2u*)(fby + off + 256);
                f32x2 q2 = *(const f32x2u*)(fby2 + off);
                f32x2 q3 = *(const f32x2u*)(fby2 + off + 256);
                f32x2 acc = q0 * w0v;
                acc = __builtin_elementwise_fma(q1, w1v, acc);
                acc = __builtin_elementwise_fma(q2, w2v, acc);
                acc = __builtin_elementwise_fma(q3, w3v, acc);
                vv[h] = acc[0] + acc[1];
            }
            a1v[jj] = pkh(vv[0], vv[1]);
        }
    )
}

extern "C" void kernel_launch(void* const* d_in, const int* in_sizes, int n_in,
                              void* d_out, int out_size, void* d_ws, size_t ws_size,
                              hipStream_t stream) {
    const float* rays_o  = (const float*)d_in[0];
    const float* rays_d  = (const float*)d_in[1];
    const float* bg      = (const float*)d_in[2];
    const float* p01     = (const float*)d_in[3];
    const float* p02     = (const float*)d_in[4];
    const float* p12     = (const float*)d_in[5];
    const float* feats   = (const float*)d_in[6];
    const float* w1      = (const float*)d_in[7];
    const float* b1      = (const float*)d_in[8];
    const float* w2      = (const float*)d_in[9];
    const float* b2      = (const float*)d_in[10];
    const float* wc1     = (const float*)d_in[11];
    const float* bc1     = (const float*)d_in[12];
    const float* wc2     = (const float*)d_in[13];
    const float* bc2     = (const float*)d_in[14];
    const float* aabb    = (const float*)d_in[15];
    float* out = (float*)d_out;

    const int use_grid = (ws_size >= (size_t)GRID16_BYTES + WSB_BYTES) ? 1 : 0;

    if (use_grid) {
        u16* wsg16 = (u16*)d_ws;
        u16* wsb = (u16*)((char*)d_ws + GRID16_BYTES);
        prep_all<<<1048, 256, 0, stream>>>(feats, wsg16, w1, wc1, w2, wc2, bc1, wsb);
        nerf_mfma_grid<<<NRAYS / 4, 256, 0, stream>>>(
            rays_o, rays_d, bg, p01, p02, p12, b1, b2, bc2, aabb, out, wsb, wsg16);
    } else {
        u16* wsb = (u16*)d_ws;
        prep_weights<<<24, 256, 0, stream>>>(w1, wc1, w2, wc2, bc1, wsb);
        nerf_mfma_planar<<<NRAYS / 4, 256, 0, stream>>>(
            rays_o, rays_d, bg, p01, p02, p12, b1, b2, bc2, aabb, out, wsb, feats);
    }
}

// Round 23
// 61.392 us; speedup vs baseline: 1.5288x; 1.0023x over previous
//
#include <hip/hip_runtime.h>

#define NS 128
#define NRAYS 8192
#define GRID16_BYTES 16777216u   // 262144 voxels * 32 ch * 2 B
#define WSB_BYTES 12288u

typedef unsigned short u16;
typedef unsigned int   u32;
typedef unsigned short u16x8 __attribute__((ext_vector_type(8)));
typedef _Float16 h16x8 __attribute__((ext_vector_type(8)));
typedef float f32x4 __attribute__((ext_vector_type(4)));
typedef float f32x2 __attribute__((ext_vector_type(2)));
typedef _Float16 h16x2 __attribute__((ext_vector_type(2)));
typedef unsigned int u32x4 __attribute__((ext_vector_type(4)));
typedef unsigned int u32x2 __attribute__((ext_vector_type(2)));
typedef float f32x2u __attribute__((ext_vector_type(2), aligned(4)));

__device__ __forceinline__ float clampf(float x, float lo, float hi) {
    return fminf(fmaxf(x, lo), hi);
}

// f32 -> f16 bits
__device__ __forceinline__ u16 f2h(float f) {
    return __builtin_bit_cast(u16, (_Float16)f);
}
// pack two f32 -> f16x2 dword (v_cvt_pkrtz_f16_f32)
__device__ __forceinline__ u32 pkh(float a, float b) {
    h16x2 v; v[0] = (_Float16)a; v[1] = (_Float16)b;
    return __builtin_bit_cast(u32, v);
}
__device__ __forceinline__ float2 uph(u32 u) {
    h16x2 v = __builtin_bit_cast(h16x2, u);
    return make_float2((float)v[0], (float)v[1]);
}
__device__ __forceinline__ f32x2 uph2(u32 u) {
    h16x2 v = __builtin_bit_cast(h16x2, u);
    f32x2 r; r[0] = (float)v[0]; r[1] = (float)v[1];
    return r;
}

__device__ __forceinline__ f32x4 mfma_f16(u16x8 a, u16x8 b, f32x4 c) {
    return __builtin_amdgcn_mfma_f32_16x16x32_f16(
        __builtin_bit_cast(h16x8, a), __builtin_bit_cast(h16x8, b), c, 0, 0, 0);
}

#define TSW(n, k) ((((n) * 64) + (k)) ^ (((n) & 7) << 3))

__device__ __forceinline__ void plane_interp(const float* __restrict__ g,
                                             float ca, float cb, float o[3]) {
    float pa = clampf((ca + 1.f) * (0.5f * 127.f), 0.f, 127.f);
    float pb = clampf((cb + 1.f) * (0.5f * 127.f), 0.f, 127.f);
    int la = (int)pa; if (la > 126) la = 126;
    int lb = (int)pb; if (lb > 126) lb = 126;
    float fa = pa - (float)la, fb = pb - (float)lb;
    const float* p = g + la * 128 + lb;
#pragma unroll
    for (int c = 0; c < 3; ++c) {
        const float* q = p + c * 16384;
        f32x2u q0 = *(const f32x2u*)q;
        f32x2u q1 = *(const f32x2u*)(q + 128);
        float top = fmaf(q0[1] - q0[0], fb, q0[0]);
        float bot = fmaf(q1[1] - q1[0], fb, q1[0]);
        o[c] = fmaf(bot - top, fa, top);
    }
}

__device__ __forceinline__ void weight_pack_item(
    int idx, const float* __restrict__ w1, const float* __restrict__ wc1,
    const float* __restrict__ w2, const float* __restrict__ wc2,
    const float* __restrict__ bc1, u16* __restrict__ wsb)
{
    int lane = (idx >> 3) & 63;
    int j = idx & 7;
    int c16 = lane & 15, kg = lane >> 4;
    float v;
    if (idx < 2048) {
        int nb = idx >> 9;
        int k = kg * 8 + j;
        v = w1[k * 64 + nb * 16 + c16];
    } else if (idx < 4096) {
        int nb = (idx - 2048) >> 9;
        int k = kg * 8 + j;
        if (k == 0)       v = 0.f;
        else if (k < 16)  v = wc1[(k + 2) * 64 + nb * 16 + c16];
        else if (k < 19)  v = wc1[(k - 16) * 64 + nb * 16 + c16];
        else if (k == 19) v = bc1[nb * 16 + c16];
        else              v = 0.f;
    } else if (idx < 5120) {
        int ks = (idx - 4096) >> 9;
        int k = ks * 32 + kg * 8 + j;
        v = w2[k * 16 + c16];
    } else {
        int ks = (idx - 5120) >> 9;
        int k = ks * 32 + kg * 8 + j;
        v = (c16 < 3) ? wc2[k * 3 + c16] : 0.f;
    }
    wsb[idx] = f2h(v);
}

// ---- merged prep: blocks 0..1023 repack grid to f16 channel-last;
//      blocks 1024..1047 pack weight A-fragments (f16) ----
__global__ __launch_bounds__(256)
void prep_all(const float* __restrict__ f, u16* __restrict__ g16,
              const float* __restrict__ w1, const float* __restrict__ wc1,
              const float* __restrict__ w2, const float* __restrict__ wc2,
              const float* __restrict__ bc1, u16* __restrict__ wsb)
{
    int bid = blockIdx.x;
    if (bid < 1024) {
        int vox = bid * 256 + threadIdx.x;
        u32 acc[16];
#pragma unroll
        for (int c = 0; c < 32; c += 2) {
            float a = f[(size_t)c * 262144 + vox];
            float b = f[(size_t)(c + 1) * 262144 + vox];
            acc[c >> 1] = pkh(a, b);
        }
        u32x4* o = (u32x4*)(g16 + (size_t)vox * 32);
#pragma unroll
        for (int k = 0; k < 4; ++k) {
            u32x4 w; w[0] = acc[k * 4]; w[1] = acc[k * 4 + 1];
            w[2] = acc[k * 4 + 2]; w[3] = acc[k * 4 + 3];
            o[k] = w;
        }
    } else {
        int idx = (bid - 1024) * 256 + threadIdx.x;
        if (idx < 6144) weight_pack_item(idx, w1, wc1, w2, wc2, bc1, wsb);
    }
}

// ---- standalone weight prep (tiny-ws fallback) ----
__global__ __launch_bounds__(256)
void prep_weights(const float* __restrict__ w1, const float* __restrict__ wc1,
                  const float* __restrict__ w2, const float* __restrict__ wc2,
                  const float* __restrict__ bc1, u16* __restrict__ wsb)
{
    int idx = blockIdx.x * 256 + threadIdx.x;
    if (idx < 6144) weight_pack_item(idx, w1, wc1, w2, wc2, bc1, wsb);
}

// relu (packed f32) then single-instruction packed f32->f16 converts
#define RELUSTORE(ACC, NB) {                                           \
        f32x2 lo_; lo_[0] = (ACC)[0]; lo_[1] = (ACC)[1];               \
        f32x2 hi_; hi_[0] = (ACC)[2]; hi_[1] = (ACC)[3];               \
        f32x2 z2_; z2_[0] = 0.f; z2_[1] = 0.f;                         \
        lo_ = __builtin_elementwise_max(lo_, z2_);                     \
        hi_ = __builtin_elementwise_max(hi_, z2_);                     \
        u32x2 wr_;                                                     \
        wr_[0] = pkh(lo_[0], lo_[1]);                                  \
        wr_[1] = pkh(hi_[0], hi_[1]);                                  \
        *(u32x2*)&s_tile[wv][TSW(c16, (NB) * 16 + kg * 4)] = wr_; }

// f16 packed corner accumulate
#define CORNERH(Q, WS) {                                               \
        p0 = __builtin_elementwise_fma(__builtin_bit_cast(h16x2, (Q)[0]), WS, p0); \
        p1 = __builtin_elementwise_fma(__builtin_bit_cast(h16x2, (Q)[1]), WS, p1); \
        p2 = __builtin_elementwise_fma(__builtin_bit_cast(h16x2, (Q)[2]), WS, p2); \
        p3 = __builtin_elementwise_fma(__builtin_bit_cast(h16x2, (Q)[3]), WS, p3); }

// shared prologue/epilogue; VARIADIC so commas inside the gather block are safe.
// AW1 (GEMM1) + AW2/AWc2 in VGPRs (f16 freed the headroom); only AWc1 stays
// in block-shared LDS -> s_wfrag 4 KB, block LDS ~28.2 KB -> 5 blocks/CU cap.
#define KERNEL_BODY(...)                                               \
    __shared__ __align__(16) u16x8 s_wfrag[256];                       \
    __shared__ __align__(16) float s_bias[96];                         \
    __shared__ __align__(16) u32x4 s_cw[4][128];                       \
    __shared__ u32   s_fb[4][128];                                     \
    __shared__ __align__(16) u16  s_tile[4][16 * 64];                  \
    __shared__ float s_tau[4][128];                                    \
    __shared__ u32   s_rgbrg[4][128];                                  \
    __shared__ u16   s_rgbb[4][128];                                   \
    const int tid  = threadIdx.x;                                      \
    const int wv   = tid >> 6;                                         \
    const int lane = tid & 63;                                         \
    const int c16  = lane & 15;                                        \
    const int kg   = lane >> 4;                                        \
    const int ray  = blockIdx.x * 4 + wv;                              \
    const int sA   = c16 + 16 * ((2 * kg) & 3);                        \
    const int sB   = c16 + 16 * ((2 * kg + 1) & 3);                    \
    u16x8 AW1[4], AW2[2], AWc2[2];                                     \
    {                                                                  \
        const u16x8* wf = (const u16x8*)wsb;                           \
        s_wfrag[tid] = wf[256 + tid];                                  \
        _Pragma("unroll")                                              \
        for (int nb = 0; nb < 4; ++nb)                                 \
            AW1[nb] = wf[nb * 64 + lane];                              \
        _Pragma("unroll")                                              \
        for (int ks = 0; ks < 2; ++ks) {                               \
            AW2[ks]  = wf[512 + ks * 64 + lane];                       \
            AWc2[ks] = wf[640 + ks * 64 + lane];                       \
        }                                                              \
    }                                                                  \
    if (tid < 96) {                                                    \
        float v;                                                       \
        if (tid < 64)      v = b1[tid];                                \
        else if (tid < 80) v = b2[tid - 64];                           \
        else               v = (tid - 80 < 3) ? bc2[tid - 80] : 0.f;   \
        s_bias[tid] = v;                                               \
    }                                                                  \
    float ox = rays_o[ray * 3 + 0], oy = rays_o[ray * 3 + 1], oz = rays_o[ray * 3 + 2]; \
    float dx = rays_d[ray * 3 + 0], dy = rays_d[ray * 3 + 1], dz = rays_d[ray * 3 + 2]; \
    float rn = rsqrtf(dx * dx + dy * dy + dz * dz);                    \
    dx *= rn; dy *= rn; dz *= rn;                                      \
    float lo0 = aabb[0], lo1 = aabb[1], lo2 = aabb[2];                 \
    float hi0 = aabb[3], hi1 = aabb[4], hi2 = aabb[5];                 \
    float invx = 1.f / dx, invy = 1.f / dy, invz = 1.f / dz;           \
    float tx0 = (lo0 - ox) * invx, tx1 = (hi0 - ox) * invx;            \
    float ty0 = (lo1 - oy) * invy, ty1 = (hi1 - oy) * invy;            \
    float tz0 = (lo2 - oz) * invz, tz1 = (hi2 - oz) * invz;            \
    float tnear = fmaxf(fmaxf(fminf(tx0, tx1), fminf(ty0, ty1)), fminf(tz0, tz1)); \
    tnear = fmaxf(tnear, 0.f);                                         \
    float tfar = fminf(fminf(fmaxf(tx0, tx1), fmaxf(ty0, ty1)), fmaxf(tz0, tz1)); \
    tfar = fmaxf(tfar, tnear);                                         \
    float delta = (tfar - tnear) * (1.f / (float)NS);                  \
    const u32 dir01 = pkh(dx, dy);                                     \
    const u32 dir2b = pkh(dz, 1.0f);                                   \
    _Pragma("unroll")                                                  \
    for (int i = 0; i < 2; ++i) {                                      \
        int s = i * 64 + lane;                                         \
        float t = tnear + delta * ((float)s + 0.5f);                   \
        float px = ox + dx * t, py = oy + dy * t, pz = oz + dz * t;    \
        px = (px - lo0) * (2.f / (hi0 - lo0)) - 1.f;                   \
        py = (py - lo1) * (2.f / (hi1 - lo1)) - 1.f;                   \
        pz = (pz - lo2) * (2.f / (hi2 - lo2)) - 1.f;                   \
        float p01[3], p02[3], p12[3];                                  \
        plane_interp(plane01, px, py, p01);                            \
        plane_interp(plane02, px, pz, p02);                            \
        plane_interp(plane12, py, pz, p12);                            \
        float gx = p01[0] * p02[0] * p12[0];                           \
        float gy = p01[1] * p02[1] * p12[1];                           \
        float gz = p01[2] * p02[2] * p12[2];                           \
        float qx = clampf((gx + 1.f) * (0.5f * 63.f), 0.f, 63.f);      \
        float qy = clampf((gy + 1.f) * (0.5f * 63.f), 0.f, 63.f);      \
        float qz = clampf((gz + 1.f) * (0.5f * 63.f), 0.f, 63.f);      \
        int ixg = (int)qx; if (ixg > 62) ixg = 62;                     \
        int iyg = (int)qy; if (iyg > 62) iyg = 62;                     \
        int izg = (int)qz; if (izg > 62) izg = 62;                     \
        float fx = qx - (float)ixg, fy = qy - (float)iyg, fz = qz - (float)izg; \
        float wx0 = 1.f - fx, wy0 = 1.f - fy, wz0 = 1.f - fz;          \
        u32x4 cw;                                                      \
        cw[0] = pkh(wx0 * wy0 * wz0, wx0 * wy0 * fz);                  \
        cw[1] = pkh(wx0 * fy  * wz0, wx0 * fy  * fz);                  \
        cw[2] = pkh(fx  * wy0 * wz0, fx  * wy0 * fz);                  \
        cw[3] = pkh(fx  * fy  * wz0, fx  * fy  * fz);                  \
        s_cw[wv][s] = cw;                                              \
        s_fb[wv][s] = (u32)(ixg * 4096 + iyg * 64 + izg);              \
    }                                                                  \
    __syncthreads();                                                   \
    _Pragma("unroll 1")                                                \
    for (int c = 0; c < 8; ++c) {                                      \
        u32x4 cwp = s_cw[wv][c * 16 + c16];                            \
        u32 vidx = s_fb[wv][c * 16 + c16];                             \
        u32x4 a1v;                                                     \
        { __VA_ARGS__ }                                                \
        u16x8 a1 = __builtin_bit_cast(u16x8, a1v);                     \
        f32x4 g0 = mfma_f16(AW1[0], a1, *(const f32x4*)&s_bias[0 * 16 + kg * 4]); \
        f32x4 g1 = mfma_f16(AW1[1], a1, *(const f32x4*)&s_bias[1 * 16 + kg * 4]); \
        f32x4 g2 = mfma_f16(AW1[2], a1, *(const f32x4*)&s_bias[2 * 16 + kg * 4]); \
        f32x4 g3 = mfma_f16(AW1[3], a1, *(const f32x4*)&s_bias[3 * 16 + kg * 4]); \
        RELUSTORE(g0, 0); RELUSTORE(g1, 1); RELUSTORE(g2, 2); RELUSTORE(g3, 3); \
        u16x8 B2_0 = *(const u16x8*)&s_tile[wv][TSW(c16, kg * 8)];     \
        u16x8 B2_1 = *(const u16x8*)&s_tile[wv][TSW(c16, 32 + kg * 8)];\
        f32x4 so = mfma_f16(AW2[0], B2_0, *(const f32x4*)&s_bias[64 + kg * 4]); \
        so = mfma_f16(AW2[1], B2_1, so);                               \
        if (kg == 0) {                                                 \
            float dens = __expf(clampf(so[0], -15.f, 15.f));           \
            s_tau[wv][c * 16 + c16] = dens * delta;                    \
        }                                                              \
        u32 Q0 = pkh(so[0], so[1]);                                    \
        u32 Q1 = pkh(so[2], so[3]);                                    \
        u32x4 ct;                                                      \
        ct[0] = (u32)__shfl((int)Q0, sA);                              \
        ct[1] = (u32)__shfl((int)Q1, sA);                              \
        ct[2] = (u32)__shfl((int)Q0, sB);                              \
        ct[3] = (u32)__shfl((int)Q1, sB);                              \
        if (kg == 2) { ct[0] = dir01; ct[1] = dir2b; ct[2] = 0u; ct[3] = 0u; } \
        if (kg == 3) { ct[0] = 0u; ct[1] = 0u; ct[2] = 0u; ct[3] = 0u; } \
        u16x8 bcin = __builtin_bit_cast(u16x8, ct);                    \
        f32x4 zz; zz[0] = zz[1] = zz[2] = zz[3] = 0.f;                 \
        f32x4 h0 = mfma_f16(s_wfrag[0 * 64 + lane], bcin, zz);         \
        f32x4 h1 = mfma_f16(s_wfrag[1 * 64 + lane], bcin, zz);         \
        f32x4 h2 = mfma_f16(s_wfrag[2 * 64 + lane], bcin, zz);         \
        f32x4 h3 = mfma_f16(s_wfrag[3 * 64 + lane], bcin, zz);         \
        RELUSTORE(h0, 0); RELUSTORE(h1, 1); RELUSTORE(h2, 2); RELUSTORE(h3, 3); \
        u16x8 B4_0 = *(const u16x8*)&s_tile[wv][TSW(c16, kg * 8)];     \
        u16x8 B4_1 = *(const u16x8*)&s_tile[wv][TSW(c16, 32 + kg * 8)];\
        f32x4 cacc = mfma_f16(AWc2[0], B4_0, *(const f32x4*)&s_bias[80 + kg * 4]); \
        cacc = mfma_f16(AWc2[1], B4_1, cacc);                          \
        if (kg == 0) {                                                 \
            int si = c * 16 + c16;                                     \
            float r = 1.f / (1.f + __expf(-cacc[0]));                  \
            float g = 1.f / (1.f + __expf(-cacc[1]));                  \
            float b = 1.f / (1.f + __expf(-cacc[2]));                  \
            s_rgbrg[wv][si] = pkh(r, g);                               \
            s_rgbb[wv][si] = (u16)(pkh(b, 0.f) & 0xffffu);             \
        }                                                              \
    }                                                                  \
    float t0 = s_tau[wv][lane];                                        \
    float t1 = s_tau[wv][64 + lane];                                   \
    float x0 = t0, x1 = t1;                                            \
    _Pragma("unroll")                                                  \
    for (int off = 1; off < 64; off <<= 1) {                           \
        float y = __shfl_up(x0, off);                                  \
        if (lane >= off) x0 += y;                                      \
    }                                                                  \
    float tot0 = __shfl(x0, 63);                                       \
    _Pragma("unroll")                                                  \
    for (int off = 1; off < 64; off <<= 1) {                           \
        float y = __shfl_up(x1, off);                                  \
        if (lane >= off) x1 += y;                                      \
    }                                                                  \
    x1 += tot0;                                                        \
    float w0 = __expf(t0 - x0) * (1.f - __expf(-t0));                  \
    float w1s = __expf(t1 - x1) * (1.f - __expf(-t1));                 \
    float2 rg0 = uph(s_rgbrg[wv][lane]);                               \
    float2 rg1 = uph(s_rgbrg[wv][64 + lane]);                          \
    float bb0 = uph((u32)s_rgbb[wv][lane]).x;                          \
    float bb1 = uph((u32)s_rgbb[wv][64 + lane]).x;                     \
    float v0 = w0 * rg0.x + w1s * rg1.x;                               \
    float v1 = w0 * rg0.y + w1s * rg1.y;                               \
    float v2 = w0 * bb0 + w1s * bb1;                                   \
    float v3 = w0 + w1s;                                               \
    _Pragma("unroll")                                                  \
    for (int off = 32; off; off >>= 1) {                               \
        v0 += __shfl_xor(v0, off);                                     \
        v1 += __shfl_xor(v1, off);                                     \
        v2 += __shfl_xor(v2, off);                                     \
        v3 += __shfl_xor(v3, off);                                     \
    }                                                                  \
    if (lane == 0) {                                                   \
        float bg = bg_color[0];                                        \
        out[ray * 3 + 0] = v0 + (1.f - v3) * bg;                       \
        out[ray * 3 + 1] = v1 + (1.f - v3) * bg;                       \
        out[ray * 3 + 2] = v2 + (1.f - v3) * bg;                       \
    }

// ---- HOT kernel: f16 channel-last grid gather, packed-f16 combine ----
__global__ __launch_bounds__(256)
void nerf_mfma_grid(const float* __restrict__ rays_o,
                    const float* __restrict__ rays_d,
                    const float* __restrict__ bg_color,
                    const float* __restrict__ plane01,
                    const float* __restrict__ plane02,
                    const float* __restrict__ plane12,
                    const float* __restrict__ b1, const float* __restrict__ b2,
                    const float* __restrict__ bc2,
                    const float* __restrict__ aabb,
                    float* __restrict__ out,
                    const u16* __restrict__ wsb,
                    const u16* __restrict__ wsg)
{
    const char* gby = (const char*)wsg;
    KERNEL_BODY(
        u32 o0  = vidx * 64u + (u32)(kg * 16);
        u32 oy  = o0 + 4096u;
        u32 ox  = o0 + 262144u;
        u32 oxy = o0 + 266240u;
        u32x4 q00 = *(const u32x4*)(gby + o0);
        u32x4 q01 = *(const u32x4*)(gby + o0 + 64);
        u32x4 q10 = *(const u32x4*)(gby + oy);
        u32x4 q11 = *(const u32x4*)(gby + oy + 64);
        u32x4 q20 = *(const u32x4*)(gby + ox);
        u32x4 q21 = *(const u32x4*)(gby + ox + 64);
        u32x4 q30 = *(const u32x4*)(gby + oxy);
        u32x4 q31 = *(const u32x4*)(gby + oxy + 64);
        h16x2 cwA = __builtin_bit_cast(h16x2, cwp[0]);
        h16x2 cwB = __builtin_bit_cast(h16x2, cwp[1]);
        h16x2 cwC = __builtin_bit_cast(h16x2, cwp[2]);
        h16x2 cwD = __builtin_bit_cast(h16x2, cwp[3]);
        h16x2 s00; s00[0] = cwA[0]; s00[1] = cwA[0];
        h16x2 s01; s01[0] = cwA[1]; s01[1] = cwA[1];
        h16x2 s10; s10[0] = cwB[0]; s10[1] = cwB[0];
        h16x2 s11; s11[0] = cwB[1]; s11[1] = cwB[1];
        h16x2 s20; s20[0] = cwC[0]; s20[1] = cwC[0];
        h16x2 s21; s21[0] = cwC[1]; s21[1] = cwC[1];
        h16x2 s30; s30[0] = cwD[0]; s30[1] = cwD[0];
        h16x2 s31; s31[0] = cwD[1]; s31[1] = cwD[1];
        h16x2 p0; p0[0] = (_Float16)0.f; p0[1] = (_Float16)0.f;
        h16x2 p1 = p0, p2 = p0, p3 = p0;
        CORNERH(q00, s00); CORNERH(q01, s01);
        CORNERH(q10, s10); CORNERH(q11, s11);
        CORNERH(q20, s20); CORNERH(q21, s21);
        CORNERH(q30, s30); CORNERH(q31, s31);
        a1v[0] = __builtin_bit_cast(u32, p0);
        a1v[1] = __builtin_bit_cast(u32, p1);
        a1v[2] = __builtin_bit_cast(u32, p2);
        a1v[3] = __builtin_bit_cast(u32, p3);
    )
}

// ---- fallback kernel: planar f32 gather (f16 output fragments) ----
__global__ __launch_bounds__(256)
void nerf_mfma_planar(const float* __restrict__ rays_o,
                      const float* __restrict__ rays_d,
                      const float* __restrict__ bg_color,
                      const float* __restrict__ plane01,
                      const float* __restrict__ plane02,
                      const float* __restrict__ plane12,
                      const float* __restrict__ b1, const float* __restrict__ b2,
                      const float* __restrict__ bc2,
                      const float* __restrict__ aabb,
                      float* __restrict__ out,
                      const u16* __restrict__ wsb,
                      const float* __restrict__ features)
{
    const char* fby  = (const char*)features;
    const char* fby2 = fby + 16384;
    KERNEL_BODY(
        f32x2 w0v = uph2(cwp[0]);
        f32x2 w1v = uph2(cwp[1]);
        f32x2 w2v = uph2(cwp[2]);
        f32x2 w3v = uph2(cwp[3]);
        u32 chb = vidx * 4u + (u32)(kg * 8) * 1048576u;
        _Pragma("unroll")
        for (int jj = 0; jj < 4; ++jj) {
            float vv[2];
            _Pragma("unroll")
            for (int h = 0; h < 2; ++h) {
                u32 off = chb + (u32)(jj * 2 + h) * 1048576u;
                f32x2 q0 = *(const f32x2u*)(fby + off);
                f32x2 q1 = *(const f32x2u*)(fby + off + 256);
                f32x2 q2 = *(const f32x2u*)(fby2 + off);
                f32x2 q3 = *(const f32x2u*)(fby2 + off + 256);
                f32x2 acc = q0 * w0v;
                acc = __builtin_elementwise_fma(q1, w1v, acc);
                acc = __builtin_elementwise_fma(q2, w2v, acc);
                acc = __builtin_elementwise_fma(q3, w3v, acc);
                vv[h] = acc[0] + acc[1];
            }
            a1v[jj] = pkh(vv[0], vv[1]);
        }
    )
}

extern "C" void kernel_launch(void* const* d_in, const int* in_sizes, int n_in,
                              void* d_out, int out_size, void* d_ws, size_t ws_size,
                              hipStream_t stream) {
    const float* rays_o  = (const float*)d_in[0];
    const float* rays_d  = (const float*)d_in[1];
    const float* bg      = (const float*)d_in[2];
    const float* p01     = (const float*)d_in[3];
    const float* p02     = (const float*)d_in[4];
    const float* p12     = (const float*)d_in[5];
    const float* feats   = (const float*)d_in[6];
    const float* w1      = (const float*)d_in[7];
    const float* b1      = (const float*)d_in[8];
    const float* w2      = (const float*)d_in[9];
    const float* b2      = (const float*)d_in[10];
    const float* wc1     = (const float*)d_in[11];
    const float* bc1     = (const float*)d_in[12];
    const float* wc2     = (const float*)d_in[13];
    const float* bc2     = (const float*)d_in[14];
    const float* aabb    = (const float*)d_in[15];
    float* out = (float*)d_out;

    const int use_grid = (ws_size >= (size_t)GRID16_BYTES + WSB_BYTES) ? 1 : 0;

    if (use_grid) {
        u16* wsg16 = (u16*)d_ws;
        u16* wsb = (u16*)((char*)d_ws + GRID16_BYTES);
        prep_all<<<1048, 256, 0, stream>>>(feats, wsg16, w1, wc1, w2, wc2, bc1, wsb);
        nerf_mfma_grid<<<NRAYS / 4, 256, 0, stream>>>(
            rays_o, rays_d, bg, p01, p02, p12, b1, b2, bc2, aabb, out, wsb, wsg16);
    } else {
        u16* wsb = (u16*)d_ws;
        prep_weights<<<24, 256, 0, stream>>>(w1, wc1, w2, wc2, bc1, wsb);
        nerf_mfma_planar<<<NRAYS / 4, 256, 0, stream>>>(
            rays_o, rays_d, bg, p01, p02, p12, b1, b2, bc2, aabb, out, wsb, feats);
    }
}